// Round 6
// baseline (153.148 us; speedup 1.0000x reference)
//
#include <hip/hip_runtime.h>

#define NN 50000
#define NNP 50048          // NN padded to multiple of 64
#define NE 800000
#define CAP 64             // per-node neighbor capacity (P(deg>64) ~ 2e-18 at lambda=16)

typedef float f32x4 __attribute__((ext_vector_type(4)));
typedef short bf16x8 __attribute__((ext_vector_type(8)));

__device__ __forceinline__ float bf2f(unsigned short u) {
    union { float f; unsigned int i; } v; v.i = ((unsigned int)u) << 16; return v.f;
}
__device__ __forceinline__ unsigned short f2bf(float f) {
    unsigned int i = __float_as_uint(f);
    unsigned int r = i + 0x7FFFu + ((i >> 16) & 1u);
    return (unsigned short)(r >> 16);
}

// ------------------------------------------- bucketed neighbor-list build
// 2 edges per thread; single 8B scattered store per edge: {src, ea_bits}.
__global__ __launch_bounds__(256) void fill_kernel(const int* __restrict__ ei,
                                                   const float* __restrict__ ea,
                                                   int* __restrict__ cur,
                                                   int2* __restrict__ slot2) {
    int t = blockIdx.x * 256 + threadIdx.x;
    if (t >= NE / 2) return;
    int2   s2 = ((const int2*)ei)[t];
    int2   d2 = ((const int2*)(ei + NE))[t];
    float2 a2 = ((const float2*)ea)[t];
    int p0 = atomicAdd(&cur[d2.x], 1);
    int p1 = atomicAdd(&cur[d2.y], 1);
    if (p0 < CAP) slot2[d2.x * CAP + p0] = make_int2(s2.x, __float_as_int(a2.x));
    if (p1 < CAP) slot2[d2.y * CAP + p1] = make_int2(s2.y, __float_as_int(a2.y));
}

// ---------------------------------------------------------------- prep
__global__ __launch_bounds__(256) void prepx_kernel(const float* __restrict__ x,
                                                    ushort* __restrict__ xh) {
    int i = blockIdx.x * 256 + threadIdx.x;   // 800000 float4 groups
    float4 v = ((const float4*)x)[i];
    ushort4 o;
    o.x = f2bf(v.x); o.y = f2bf(v.y); o.z = f2bf(v.z); o.w = f2bf(v.w);
    ((ushort4*)xh)[i] = o;
}

// pack weights into per-lane-contiguous MFMA B-fragment layout:
// Gp[((kk*8+n16)*64+l)*8+j] = G[kk*32+(l>>4)*8+j][n16*16+(l&15)]
__global__ __launch_bounds__(256) void prepw_kernel(const float* __restrict__ W1,
                                                    const float* __restrict__ b1,
                                                    const float* __restrict__ W2,
                                                    ushort* __restrict__ G1p,
                                                    ushort* __restrict__ G2p) {
    int id = blockIdx.x * 256 + threadIdx.x;
    if (id < 20480) {                 // G1: 160x128 (W1 129 rows + b1 + zero pad)
        int j = id & 7, l = (id >> 3) & 63, t = id >> 9;
        int kk = t >> 3, n16 = t & 7;
        int k = kk * 32 + ((l >> 4) * 8) + j, n = n16 * 16 + (l & 15);
        float v = (k < 129) ? W1[k * 128 + n] : ((k == 129) ? b1[n] : 0.f);
        G1p[id] = f2bf(v);
    } else if (id < 20480 + 16384) {  // G2: 128x128 = [W2i | W2j]
        int id2 = id - 20480;
        int j = id2 & 7, l = (id2 >> 3) & 63, t = id2 >> 9;
        int kk = t >> 3, n16 = t & 7;
        int k = kk * 32 + ((l >> 4) * 8) + j, n = n16 * 16 + (l & 15);
        float v = (n < 64) ? W2[k * 64 + n] : W2[(128 + k) * 64 + (n - 64)];
        G2p[id2] = f2bf(v);
    }
}

// -------------------------------------------------- layer-1 gather -> F1b
// F1b row (bf16, stride 160): [0:64)=(deg+1)*x, [64:128)=x+sum_nb, [128]=sea,
// [129]=deg+1, [130:160)=0. Also writes seaf[node] (f32) for final_kernel.
__global__ __launch_bounds__(256) void agg1_kernel(const float* __restrict__ x,
                                                   const ushort* __restrict__ xh,
                                                   const int* __restrict__ cur,
                                                   const int2* __restrict__ slot2,
                                                   ushort* __restrict__ F1b,
                                                   float* __restrict__ seaf) {
    __shared__ int sIdx[4][64];
    int wid2 = threadIdx.x >> 6;
    int node = blockIdx.x * 4 + wid2;
    int c = threadIdx.x & 63;
    ushort* row = F1b + (size_t)node * 160;
    if (node >= NN) {                 // zero pad rows (avoid garbage in MFMA)
        row[c] = 0; row[64 + c] = 0; if (c < 32) row[128 + c] = 0;
        return;
    }
    int cnt = cur[node]; cnt = cnt < CAP ? cnt : CAP;
    // coalesced neighbor {index, ea} for this node
    int2 se = (c < cnt) ? slot2[node * CAP + c] : make_int2(0, 0);
    float eav = (c < cnt) ? __int_as_float(se.y) : 0.f;
    sIdx[wid2][c] = (c < cnt) ? se.x : 0;
#pragma unroll
    for (int o = 1; o < 64; o <<= 1) eav += __shfl_xor(eav, o);   // sea (all lanes)
    float xv = x[node * 64 + c];
    float acc = xv;                   // self loop
    int j = 0;
    for (; j + 8 <= cnt; j += 8) {
        int s0 = sIdx[wid2][j + 0], s1 = sIdx[wid2][j + 1];
        int s2 = sIdx[wid2][j + 2], s3 = sIdx[wid2][j + 3];
        int s4 = sIdx[wid2][j + 4], s5 = sIdx[wid2][j + 5];
        int s6 = sIdx[wid2][j + 6], s7 = sIdx[wid2][j + 7];
        float a0 = bf2f(xh[s0 * 64 + c]), a1 = bf2f(xh[s1 * 64 + c]);
        float a2 = bf2f(xh[s2 * 64 + c]), a3 = bf2f(xh[s3 * 64 + c]);
        float a4 = bf2f(xh[s4 * 64 + c]), a5 = bf2f(xh[s5 * 64 + c]);
        float a6 = bf2f(xh[s6 * 64 + c]), a7 = bf2f(xh[s7 * 64 + c]);
        acc += ((a0 + a1) + (a2 + a3)) + ((a4 + a5) + (a6 + a7));
    }
    for (; j < cnt; ++j) {
        int s = sIdx[wid2][j];
        acc += bf2f(xh[s * 64 + c]);
    }
    float degp = (float)(cnt + 1);
    row[c] = f2bf(degp * xv);
    row[64 + c] = f2bf(acc);
    if (c < 32) {
        ushort z = 0;
        if (c == 0) z = f2bf(eav);
        else if (c == 1) z = f2bf(degp);
        row[128 + c] = z;
    }
    if (c == 0) seaf[node] = eav;
}

// -------------------------------------------------- GEMM1: h = relu(F1b @ G1)
__global__ __launch_bounds__(256) void gemm1_kernel(const ushort* __restrict__ F1b,
                                                    const bf16x8* __restrict__ G1p,
                                                    ushort* __restrict__ h) {
    int w = threadIdx.x >> 6, lane = threadIdx.x & 63;
    int node0 = blockIdx.x * 64;
    int ar = lane & 15, ak = (lane >> 4) * 8;
    f32x4 z = {0.f, 0.f, 0.f, 0.f};
    f32x4 acc[4][2];
#pragma unroll
    for (int mr = 0; mr < 4; ++mr) { acc[mr][0] = z; acc[mr][1] = z; }
#pragma unroll
    for (int kk = 0; kk < 5; ++kk) {
        bf16x8 b0 = G1p[(kk * 8 + w * 2 + 0) * 64 + lane];
        bf16x8 b1 = G1p[(kk * 8 + w * 2 + 1) * 64 + lane];
#pragma unroll
        for (int mr = 0; mr < 4; ++mr) {
            bf16x8 a = *(const bf16x8*)(F1b + (size_t)(node0 + mr * 16 + ar) * 160 + kk * 32 + ak);
            acc[mr][0] = __builtin_amdgcn_mfma_f32_16x16x32_bf16(a, b0, acc[mr][0], 0, 0, 0);
            acc[mr][1] = __builtin_amdgcn_mfma_f32_16x16x32_bf16(a, b1, acc[mr][1], 0, 0, 0);
        }
    }
    int crow = (lane >> 4) * 4, ccol = lane & 15;
#pragma unroll
    for (int mr = 0; mr < 4; ++mr)
#pragma unroll
        for (int nc = 0; nc < 2; ++nc)
#pragma unroll
            for (int r = 0; r < 4; ++r) {
                int row = node0 + mr * 16 + crow + r;   // write ALL NNP rows:
                int col = w * 32 + nc * 16 + ccol;      // replays must never read poison
                h[(size_t)row * 128 + col] = f2bf(fmaxf(acc[mr][nc][r], 0.f));
            }
}

// -------------------------------------- GEMM2: [P2|Q2] = h @ [W2i|W2j]
__global__ __launch_bounds__(256) void gemm2_kernel(const ushort* __restrict__ hb,
                                                    const bf16x8* __restrict__ G2p,
                                                    float* __restrict__ P2,
                                                    ushort* __restrict__ Q2) {
    int w = threadIdx.x >> 6, lane = threadIdx.x & 63;
    int node0 = blockIdx.x * 64;
    int ar = lane & 15, ak = (lane >> 4) * 8;
    f32x4 z = {0.f, 0.f, 0.f, 0.f};
    f32x4 acc[4][2];
#pragma unroll
    for (int mr = 0; mr < 4; ++mr) { acc[mr][0] = z; acc[mr][1] = z; }
#pragma unroll
    for (int kk = 0; kk < 4; ++kk) {
        bf16x8 b0 = G2p[(kk * 8 + w * 2 + 0) * 64 + lane];
        bf16x8 b1 = G2p[(kk * 8 + w * 2 + 1) * 64 + lane];
#pragma unroll
        for (int mr = 0; mr < 4; ++mr) {
            bf16x8 a = *(const bf16x8*)(hb + (size_t)(node0 + mr * 16 + ar) * 128 + kk * 32 + ak);
            acc[mr][0] = __builtin_amdgcn_mfma_f32_16x16x32_bf16(a, b0, acc[mr][0], 0, 0, 0);
            acc[mr][1] = __builtin_amdgcn_mfma_f32_16x16x32_bf16(a, b1, acc[mr][1], 0, 0, 0);
        }
    }
    int crow = (lane >> 4) * 4, ccol = lane & 15;
#pragma unroll
    for (int mr = 0; mr < 4; ++mr)
#pragma unroll
        for (int nc = 0; nc < 2; ++nc)
#pragma unroll
            for (int r = 0; r < 4; ++r) {
                int row = node0 + mr * 16 + crow + r;
                int col = w * 32 + nc * 16 + ccol;   // wave-uniform branch
                if (col < 64) P2[(size_t)row * 64 + col] = acc[mr][nc][r];
                else          Q2[(size_t)row * 64 + (col - 64)] = f2bf(acc[mr][nc][r]);
            }
}

// ---------------------- final: gather Q2, combine, relu, log_softmax
__global__ __launch_bounds__(256) void final_kernel(const float* __restrict__ P2,
                                                    const ushort* __restrict__ Q2,
                                                    const int* __restrict__ cur,
                                                    const int2* __restrict__ slot2,
                                                    const float* __restrict__ seaf,
                                                    const float* __restrict__ W2,
                                                    const float* __restrict__ b2,
                                                    float* __restrict__ out) {
    __shared__ int sIdx[4][64];
    int wid2 = threadIdx.x >> 6;
    int node = blockIdx.x * 4 + wid2;
    int c = threadIdx.x & 63;
    int cnt = cur[node]; cnt = cnt < CAP ? cnt : CAP;
    sIdx[wid2][c] = (c < cnt) ? slot2[node * CAP + c].x : 0;   // coalesced indices
    float acc = bf2f(Q2[(size_t)node * 64 + c]);               // self loop
    int j = 0;
    for (; j + 8 <= cnt; j += 8) {
        int s0 = sIdx[wid2][j + 0], s1 = sIdx[wid2][j + 1];
        int s2 = sIdx[wid2][j + 2], s3 = sIdx[wid2][j + 3];
        int s4 = sIdx[wid2][j + 4], s5 = sIdx[wid2][j + 5];
        int s6 = sIdx[wid2][j + 6], s7 = sIdx[wid2][j + 7];
        float a0 = bf2f(Q2[(size_t)s0 * 64 + c]), a1 = bf2f(Q2[(size_t)s1 * 64 + c]);
        float a2 = bf2f(Q2[(size_t)s2 * 64 + c]), a3 = bf2f(Q2[(size_t)s3 * 64 + c]);
        float a4 = bf2f(Q2[(size_t)s4 * 64 + c]), a5 = bf2f(Q2[(size_t)s5 * 64 + c]);
        float a6 = bf2f(Q2[(size_t)s6 * 64 + c]), a7 = bf2f(Q2[(size_t)s7 * 64 + c]);
        acc += ((a0 + a1) + (a2 + a3)) + ((a4 + a5) + (a6 + a7));
    }
    for (; j < cnt; ++j) {
        int s = sIdx[wid2][j];
        acc += bf2f(Q2[(size_t)s * 64 + c]);
    }
    float degp = (float)(cnt + 1);
    float v = degp * P2[(size_t)node * 64 + c] + acc
            + seaf[node] * W2[256 * 64 + c] + degp * b2[c];
    v = fmaxf(v, 0.f);
    float m = v;
#pragma unroll
    for (int o = 1; o < 64; o <<= 1) m = fmaxf(m, __shfl_xor(m, o));
    float s2 = __expf(v - m);
#pragma unroll
    for (int o = 1; o < 64; o <<= 1) s2 += __shfl_xor(s2, o);
    out[(size_t)node * 64 + c] = v - m - __logf(s2);
}

// ---------------------------------------------------------------- launcher
extern "C" void kernel_launch(void* const* d_in, const int* in_sizes, int n_in,
                              void* d_out, int out_size, void* d_ws, size_t ws_size,
                              hipStream_t stream) {
    const float* x  = (const float*)d_in[0];
    const int*   ei = (const int*)d_in[1];
    const float* ea = (const float*)d_in[2];
    const float* W1 = (const float*)d_in[3];
    const float* b1 = (const float*)d_in[4];
    const float* W2 = (const float*)d_in[5];
    const float* b2 = (const float*)d_in[6];
    float* out = (float*)d_out;

    char* ws = (char*)d_ws;
    size_t off_b = 0;
    auto take = [&](size_t bytes) -> void* {
        void* p = ws + off_b;
        off_b += (bytes + 255) & ~(size_t)255;
        return p;
    };
    int*    cur   = (int*)take((size_t)NN * 4);        // zeroed below
    size_t zero_bytes = off_b;
    int2*   slot2 = (int2*)take((size_t)NN * CAP * 8);
    float*  seaf  = (float*)take((size_t)NN * 4);
    ushort* xh    = (ushort*)take((size_t)NN * 64 * 2);
    ushort* F1b   = (ushort*)take((size_t)NNP * 160 * 2);
    ushort* h     = (ushort*)take((size_t)NNP * 128 * 2);
    float*  P2    = (float*)take((size_t)NNP * 64 * 4);
    ushort* Q2    = (ushort*)take((size_t)NNP * 64 * 2);
    ushort* G1p   = (ushort*)take(20480 * 2);
    ushort* G2p   = (ushort*)take(16384 * 2);
    (void)in_sizes; (void)n_in; (void)out_size; (void)ws_size;

    hipMemsetAsync(d_ws, 0, zero_bytes, stream);
    fill_kernel<<<(NE / 2 + 255) / 256, 256, 0, stream>>>(ei, ea, cur, slot2);
    prepx_kernel<<<3125, 256, 0, stream>>>(x, xh);
    prepw_kernel<<<144, 256, 0, stream>>>(W1, b1, W2, G1p, G2p);
    agg1_kernel<<<NNP / 4, 256, 0, stream>>>(x, xh, cur, slot2, F1b, seaf);
    gemm1_kernel<<<NNP / 64, 256, 0, stream>>>(F1b, (const bf16x8*)G1p, h);
    gemm2_kernel<<<NNP / 64, 256, 0, stream>>>(h, (const bf16x8*)G2p, P2, Q2);
    final_kernel<<<NN / 4, 256, 0, stream>>>(P2, Q2, cur, slot2, seaf, W2, b2, out);
}

// Round 7
// 129.780 us; speedup vs baseline: 1.1801x; 1.1801x over previous
//
#include <hip/hip_runtime.h>

#define NN 50000
#define NNP 50048          // NN padded to multiple of 64
#define NE 800000
#define CAP 64             // per-node neighbor capacity (P(deg>64) ~ 2e-18 at lambda=16)

#define NBINS 512          // coarse bins by dst>>7 (bins 391..511 empty)
#define BINSHIFT 7
#define BINCAP 2560        // max edges/bin: lambda ~2046, +11 sigma
#define ACHUNK 6400        // edges per binA block: 125 * 6400 = 800000 exactly
#define NBLK_A 125
#define NBLK_B 391         // (NN + 127) >> 7

typedef float f32x4 __attribute__((ext_vector_type(4)));
typedef short bf16x8 __attribute__((ext_vector_type(8)));

__device__ __forceinline__ float bf2f(unsigned short u) {
    union { float f; unsigned int i; } v; v.i = ((unsigned int)u) << 16; return v.f;
}
__device__ __forceinline__ unsigned short f2bf(float f) {
    unsigned int i = __float_as_uint(f);
    unsigned int r = i + 0x7FFFu + ((i >> 16) & 1u);
    return (unsigned short)(r >> 16);
}

// ---------------- STEP A: coarse partition by dst>>7, LDS histogram,
// one global atomic per (block,bin) instead of one per edge.
__global__ __launch_bounds__(256) void binA_kernel(const int* __restrict__ ei,
                                                   const float* __restrict__ ea,
                                                   int* __restrict__ gcur,
                                                   int2* __restrict__ coarse) {
    __shared__ int hist[NBINS], curl[NBINS], basel[NBINS];
    int tid = threadIdx.x;
    for (int b = tid; b < NBINS; b += 256) { hist[b] = 0; curl[b] = 0; }
    __syncthreads();
    int e0 = blockIdx.x * ACHUNK;
    for (int i = tid; i < ACHUNK; i += 256) {            // phase 1: histogram
        int d = ei[NE + e0 + i];
        atomicAdd(&hist[d >> BINSHIFT], 1);
    }
    __syncthreads();
    for (int b = tid; b < NBINS; b += 256)               // phase 2: reserve ranges
        basel[b] = atomicAdd(&gcur[b], hist[b]);
    __syncthreads();
    for (int i = tid; i < ACHUNK; i += 256) {            // phase 3: scatter records
        int e = e0 + i;
        int s = ei[e];
        int d = ei[NE + e];
        float a = ea[e];
        int b = d >> BINSHIFT;
        int p = atomicAdd(&curl[b], 1) + basel[b];
        if (p < BINCAP)
            coarse[(size_t)b * BINCAP + p] = make_int2(s | ((d & 127) << 16),
                                                       __float_as_int(a));
    }
}

// ---------------- STEP B: per-bin fine placement, LDS atomics only.
// Also writes cur[node] (degree) -> no global memset of cur needed.
__global__ __launch_bounds__(256) void binB_kernel(const int* __restrict__ gcur,
                                                   const int2* __restrict__ coarse,
                                                   int* __restrict__ cur,
                                                   int2* __restrict__ slot2) {
    __shared__ int curl[128];
    int b = blockIdx.x, tid = threadIdx.x;
    if (tid < 128) curl[tid] = 0;
    __syncthreads();
    int n = gcur[b]; n = n < BINCAP ? n : BINCAP;
    for (int i = tid; i < n; i += 256) {
        int2 rec = coarse[(size_t)b * BINCAP + i];
        int s = rec.x & 0xFFFF;
        int dl = (rec.x >> 16) & 127;
        int p = atomicAdd(&curl[dl], 1);
        if (p < CAP) slot2[((size_t)((b << BINSHIFT) + dl)) * CAP + p] = make_int2(s, rec.y);
    }
    __syncthreads();
    if (tid < 128) {
        int node = (b << BINSHIFT) + tid;
        if (node < NN) cur[node] = curl[tid];
    }
}

// ---------------------------------------------------------------- prep
__global__ __launch_bounds__(256) void prepx_kernel(const float* __restrict__ x,
                                                    ushort* __restrict__ xh) {
    int i = blockIdx.x * 256 + threadIdx.x;   // 800000 float4 groups
    float4 v = ((const float4*)x)[i];
    ushort4 o;
    o.x = f2bf(v.x); o.y = f2bf(v.y); o.z = f2bf(v.z); o.w = f2bf(v.w);
    ((ushort4*)xh)[i] = o;
}

// pack weights into per-lane-contiguous MFMA B-fragment layout:
// Gp[((kk*8+n16)*64+l)*8+j] = G[kk*32+(l>>4)*8+j][n16*16+(l&15)]
__global__ __launch_bounds__(256) void prepw_kernel(const float* __restrict__ W1,
                                                    const float* __restrict__ b1,
                                                    const float* __restrict__ W2,
                                                    ushort* __restrict__ G1p,
                                                    ushort* __restrict__ G2p) {
    int id = blockIdx.x * 256 + threadIdx.x;
    if (id < 20480) {                 // G1: 160x128 (W1 129 rows + b1 + zero pad)
        int j = id & 7, l = (id >> 3) & 63, t = id >> 9;
        int kk = t >> 3, n16 = t & 7;
        int k = kk * 32 + ((l >> 4) * 8) + j, n = n16 * 16 + (l & 15);
        float v = (k < 129) ? W1[k * 128 + n] : ((k == 129) ? b1[n] : 0.f);
        G1p[id] = f2bf(v);
    } else if (id < 20480 + 16384) {  // G2: 128x128 = [W2i | W2j]
        int id2 = id - 20480;
        int j = id2 & 7, l = (id2 >> 3) & 63, t = id2 >> 9;
        int kk = t >> 3, n16 = t & 7;
        int k = kk * 32 + ((l >> 4) * 8) + j, n = n16 * 16 + (l & 15);
        float v = (n < 64) ? W2[k * 64 + n] : W2[(128 + k) * 64 + (n - 64)];
        G2p[id2] = f2bf(v);
    }
}

// -------------------------------------------------- layer-1 gather -> F1b
// F1b row (bf16, stride 160): [0:64)=(deg+1)*x, [64:128)=x+sum_nb, [128]=sea,
// [129]=deg+1, [130:160)=0. Also writes seaf[node] (f32) for final_kernel.
__global__ __launch_bounds__(256) void agg1_kernel(const float* __restrict__ x,
                                                   const ushort* __restrict__ xh,
                                                   const int* __restrict__ cur,
                                                   const int2* __restrict__ slot2,
                                                   ushort* __restrict__ F1b,
                                                   float* __restrict__ seaf) {
    __shared__ int sIdx[4][64];
    int wid2 = threadIdx.x >> 6;
    int node = blockIdx.x * 4 + wid2;
    int c = threadIdx.x & 63;
    ushort* row = F1b + (size_t)node * 160;
    if (node >= NN) {                 // zero pad rows (avoid garbage in MFMA)
        row[c] = 0; row[64 + c] = 0; if (c < 32) row[128 + c] = 0;
        return;
    }
    int cnt = cur[node]; cnt = cnt < CAP ? cnt : CAP;
    // coalesced neighbor {index, ea} for this node
    int2 se = (c < cnt) ? slot2[node * CAP + c] : make_int2(0, 0);
    float eav = (c < cnt) ? __int_as_float(se.y) : 0.f;
    sIdx[wid2][c] = (c < cnt) ? se.x : 0;
#pragma unroll
    for (int o = 1; o < 64; o <<= 1) eav += __shfl_xor(eav, o);   // sea (all lanes)
    float xv = x[node * 64 + c];
    float acc = xv;                   // self loop
    int j = 0;
    for (; j + 8 <= cnt; j += 8) {
        int s0 = sIdx[wid2][j + 0], s1 = sIdx[wid2][j + 1];
        int s2 = sIdx[wid2][j + 2], s3 = sIdx[wid2][j + 3];
        int s4 = sIdx[wid2][j + 4], s5 = sIdx[wid2][j + 5];
        int s6 = sIdx[wid2][j + 6], s7 = sIdx[wid2][j + 7];
        float a0 = bf2f(xh[s0 * 64 + c]), a1 = bf2f(xh[s1 * 64 + c]);
        float a2 = bf2f(xh[s2 * 64 + c]), a3 = bf2f(xh[s3 * 64 + c]);
        float a4 = bf2f(xh[s4 * 64 + c]), a5 = bf2f(xh[s5 * 64 + c]);
        float a6 = bf2f(xh[s6 * 64 + c]), a7 = bf2f(xh[s7 * 64 + c]);
        acc += ((a0 + a1) + (a2 + a3)) + ((a4 + a5) + (a6 + a7));
    }
    for (; j < cnt; ++j) {
        int s = sIdx[wid2][j];
        acc += bf2f(xh[s * 64 + c]);
    }
    float degp = (float)(cnt + 1);
    row[c] = f2bf(degp * xv);
    row[64 + c] = f2bf(acc);
    if (c < 32) {
        ushort z = 0;
        if (c == 0) z = f2bf(eav);
        else if (c == 1) z = f2bf(degp);
        row[128 + c] = z;
    }
    if (c == 0) seaf[node] = eav;
}

// -------------------------------------------------- GEMM1: h = relu(F1b @ G1)
__global__ __launch_bounds__(256) void gemm1_kernel(const ushort* __restrict__ F1b,
                                                    const bf16x8* __restrict__ G1p,
                                                    ushort* __restrict__ h) {
    int w = threadIdx.x >> 6, lane = threadIdx.x & 63;
    int node0 = blockIdx.x * 64;
    int ar = lane & 15, ak = (lane >> 4) * 8;
    f32x4 z = {0.f, 0.f, 0.f, 0.f};
    f32x4 acc[4][2];
#pragma unroll
    for (int mr = 0; mr < 4; ++mr) { acc[mr][0] = z; acc[mr][1] = z; }
#pragma unroll
    for (int kk = 0; kk < 5; ++kk) {
        bf16x8 b0 = G1p[(kk * 8 + w * 2 + 0) * 64 + lane];
        bf16x8 b1 = G1p[(kk * 8 + w * 2 + 1) * 64 + lane];
#pragma unroll
        for (int mr = 0; mr < 4; ++mr) {
            bf16x8 a = *(const bf16x8*)(F1b + (size_t)(node0 + mr * 16 + ar) * 160 + kk * 32 + ak);
            acc[mr][0] = __builtin_amdgcn_mfma_f32_16x16x32_bf16(a, b0, acc[mr][0], 0, 0, 0);
            acc[mr][1] = __builtin_amdgcn_mfma_f32_16x16x32_bf16(a, b1, acc[mr][1], 0, 0, 0);
        }
    }
    int crow = (lane >> 4) * 4, ccol = lane & 15;
#pragma unroll
    for (int mr = 0; mr < 4; ++mr)
#pragma unroll
        for (int nc = 0; nc < 2; ++nc)
#pragma unroll
            for (int r = 0; r < 4; ++r) {
                int row = node0 + mr * 16 + crow + r;   // write ALL NNP rows:
                int col = w * 32 + nc * 16 + ccol;      // replays must never read poison
                h[(size_t)row * 128 + col] = f2bf(fmaxf(acc[mr][nc][r], 0.f));
            }
}

// -------------------------------------- GEMM2: [P2|Q2] = h @ [W2i|W2j]
__global__ __launch_bounds__(256) void gemm2_kernel(const ushort* __restrict__ hb,
                                                    const bf16x8* __restrict__ G2p,
                                                    float* __restrict__ P2,
                                                    ushort* __restrict__ Q2) {
    int w = threadIdx.x >> 6, lane = threadIdx.x & 63;
    int node0 = blockIdx.x * 64;
    int ar = lane & 15, ak = (lane >> 4) * 8;
    f32x4 z = {0.f, 0.f, 0.f, 0.f};
    f32x4 acc[4][2];
#pragma unroll
    for (int mr = 0; mr < 4; ++mr) { acc[mr][0] = z; acc[mr][1] = z; }
#pragma unroll
    for (int kk = 0; kk < 4; ++kk) {
        bf16x8 b0 = G2p[(kk * 8 + w * 2 + 0) * 64 + lane];
        bf16x8 b1 = G2p[(kk * 8 + w * 2 + 1) * 64 + lane];
#pragma unroll
        for (int mr = 0; mr < 4; ++mr) {
            bf16x8 a = *(const bf16x8*)(hb + (size_t)(node0 + mr * 16 + ar) * 128 + kk * 32 + ak);
            acc[mr][0] = __builtin_amdgcn_mfma_f32_16x16x32_bf16(a, b0, acc[mr][0], 0, 0, 0);
            acc[mr][1] = __builtin_amdgcn_mfma_f32_16x16x32_bf16(a, b1, acc[mr][1], 0, 0, 0);
        }
    }
    int crow = (lane >> 4) * 4, ccol = lane & 15;
#pragma unroll
    for (int mr = 0; mr < 4; ++mr)
#pragma unroll
        for (int nc = 0; nc < 2; ++nc)
#pragma unroll
            for (int r = 0; r < 4; ++r) {
                int row = node0 + mr * 16 + crow + r;
                int col = w * 32 + nc * 16 + ccol;   // wave-uniform branch
                if (col < 64) P2[(size_t)row * 64 + col] = acc[mr][nc][r];
                else          Q2[(size_t)row * 64 + (col - 64)] = f2bf(acc[mr][nc][r]);
            }
}

// ---------------------- final: gather Q2, combine, relu, log_softmax
__global__ __launch_bounds__(256) void final_kernel(const float* __restrict__ P2,
                                                    const ushort* __restrict__ Q2,
                                                    const int* __restrict__ cur,
                                                    const int2* __restrict__ slot2,
                                                    const float* __restrict__ seaf,
                                                    const float* __restrict__ W2,
                                                    const float* __restrict__ b2,
                                                    float* __restrict__ out) {
    __shared__ int sIdx[4][64];
    int wid2 = threadIdx.x >> 6;
    int node = blockIdx.x * 4 + wid2;
    int c = threadIdx.x & 63;
    int cnt = cur[node]; cnt = cnt < CAP ? cnt : CAP;
    sIdx[wid2][c] = (c < cnt) ? slot2[node * CAP + c].x : 0;   // coalesced indices
    float acc = bf2f(Q2[(size_t)node * 64 + c]);               // self loop
    int j = 0;
    for (; j + 8 <= cnt; j += 8) {
        int s0 = sIdx[wid2][j + 0], s1 = sIdx[wid2][j + 1];
        int s2 = sIdx[wid2][j + 2], s3 = sIdx[wid2][j + 3];
        int s4 = sIdx[wid2][j + 4], s5 = sIdx[wid2][j + 5];
        int s6 = sIdx[wid2][j + 6], s7 = sIdx[wid2][j + 7];
        float a0 = bf2f(Q2[(size_t)s0 * 64 + c]), a1 = bf2f(Q2[(size_t)s1 * 64 + c]);
        float a2 = bf2f(Q2[(size_t)s2 * 64 + c]), a3 = bf2f(Q2[(size_t)s3 * 64 + c]);
        float a4 = bf2f(Q2[(size_t)s4 * 64 + c]), a5 = bf2f(Q2[(size_t)s5 * 64 + c]);
        float a6 = bf2f(Q2[(size_t)s6 * 64 + c]), a7 = bf2f(Q2[(size_t)s7 * 64 + c]);
        acc += ((a0 + a1) + (a2 + a3)) + ((a4 + a5) + (a6 + a7));
    }
    for (; j < cnt; ++j) {
        int s = sIdx[wid2][j];
        acc += bf2f(Q2[(size_t)s * 64 + c]);
    }
    float degp = (float)(cnt + 1);
    float v = degp * P2[(size_t)node * 64 + c] + acc
            + seaf[node] * W2[256 * 64 + c] + degp * b2[c];
    v = fmaxf(v, 0.f);
    float m = v;
#pragma unroll
    for (int o = 1; o < 64; o <<= 1) m = fmaxf(m, __shfl_xor(m, o));
    float s2 = __expf(v - m);
#pragma unroll
    for (int o = 1; o < 64; o <<= 1) s2 += __shfl_xor(s2, o);
    out[(size_t)node * 64 + c] = v - m - __logf(s2);
}

// ---------------------------------------------------------------- launcher
extern "C" void kernel_launch(void* const* d_in, const int* in_sizes, int n_in,
                              void* d_out, int out_size, void* d_ws, size_t ws_size,
                              hipStream_t stream) {
    const float* x  = (const float*)d_in[0];
    const int*   ei = (const int*)d_in[1];
    const float* ea = (const float*)d_in[2];
    const float* W1 = (const float*)d_in[3];
    const float* b1 = (const float*)d_in[4];
    const float* W2 = (const float*)d_in[5];
    const float* b2 = (const float*)d_in[6];
    float* out = (float*)d_out;

    char* ws = (char*)d_ws;
    size_t off_b = 0;
    auto take = [&](size_t bytes) -> void* {
        void* p = ws + off_b;
        off_b += (bytes + 255) & ~(size_t)255;
        return p;
    };
    int*    gcur   = (int*)take((size_t)NBINS * 4);     // zeroed below
    size_t zero_bytes = off_b;
    int2*   coarse = (int2*)take((size_t)NBINS * BINCAP * 8);
    int*    cur    = (int*)take((size_t)NN * 4);        // fully written by binB
    int2*   slot2  = (int2*)take((size_t)NN * CAP * 8);
    float*  seaf   = (float*)take((size_t)NN * 4);
    ushort* xh     = (ushort*)take((size_t)NN * 64 * 2);
    ushort* F1b    = (ushort*)take((size_t)NNP * 160 * 2);
    ushort* h      = (ushort*)take((size_t)NNP * 128 * 2);
    float*  P2     = (float*)take((size_t)NNP * 64 * 4);
    ushort* Q2     = (ushort*)take((size_t)NNP * 64 * 2);
    ushort* G1p    = (ushort*)take(20480 * 2);
    ushort* G2p    = (ushort*)take(16384 * 2);
    (void)in_sizes; (void)n_in; (void)out_size; (void)ws_size;

    hipMemsetAsync(d_ws, 0, zero_bytes, stream);
    binA_kernel<<<NBLK_A, 256, 0, stream>>>(ei, ea, gcur, coarse);
    binB_kernel<<<NBLK_B, 256, 0, stream>>>(gcur, coarse, cur, slot2);
    prepx_kernel<<<3125, 256, 0, stream>>>(x, xh);
    prepw_kernel<<<144, 256, 0, stream>>>(W1, b1, W2, G1p, G2p);
    agg1_kernel<<<NNP / 4, 256, 0, stream>>>(x, xh, cur, slot2, F1b, seaf);
    gemm1_kernel<<<NNP / 64, 256, 0, stream>>>(F1b, (const bf16x8*)G1p, h);
    gemm2_kernel<<<NNP / 64, 256, 0, stream>>>(h, (const bf16x8*)G2p, P2, Q2);
    final_kernel<<<NN / 4, 256, 0, stream>>>(P2, Q2, cur, slot2, seaf, W2, b2, out);
}

// Round 8
// 126.003 us; speedup vs baseline: 1.2154x; 1.0300x over previous
//
#include <hip/hip_runtime.h>

#define NN 50000
#define NNP 50048          // NN padded to multiple of 64
#define NE 800000
#define CAP 64             // per-node neighbor capacity (P(deg>64) ~ 2e-18 at lambda=16)

#define NBINS 512          // coarse bins by dst>>7 (bins 391..511 empty)
#define BINSHIFT 7
#define BINCAP 2560        // max edges/bin: lambda ~2046, +11 sigma
#define ACHUNK 6400        // edges per binA block: 125 * 6400 = 800000 exactly
#define NBLK_A 125
#define NBLK_B 391         // (NN + 127) >> 7

typedef float f32x4 __attribute__((ext_vector_type(4)));
typedef short bf16x8 __attribute__((ext_vector_type(8)));

__device__ __forceinline__ float bf2f(unsigned short u) {
    union { float f; unsigned int i; } v; v.i = ((unsigned int)u) << 16; return v.f;
}
__device__ __forceinline__ unsigned short f2bf(float f) {
    unsigned int i = __float_as_uint(f);
    unsigned int r = i + 0x7FFFu + ((i >> 16) & 1u);
    return (unsigned short)(r >> 16);
}

// ---------------------------------------------------------------- prep
// Also zeroes gcur (512 ints) so no hipMemsetAsync is needed in the graph
// (a 2KB fillBufferAligned dispatch measured 42 us per replay — round 7).
__global__ __launch_bounds__(256) void prepx_kernel(const float* __restrict__ x,
                                                    ushort* __restrict__ xh,
                                                    int* __restrict__ gcur) {
    int i = blockIdx.x * 256 + threadIdx.x;   // 800000 float4 groups
    if (blockIdx.x == 0 && threadIdx.x < NBINS / 4)
        ((int4*)gcur)[threadIdx.x] = make_int4(0, 0, 0, 0);
    float4 v = ((const float4*)x)[i];
    ushort4 o;
    o.x = f2bf(v.x); o.y = f2bf(v.y); o.z = f2bf(v.z); o.w = f2bf(v.w);
    ((ushort4*)xh)[i] = o;
}

// ---------------- STEP A: coarse partition by dst>>7, LDS histogram,
// one global atomic per (block,bin) instead of one per edge.
__global__ __launch_bounds__(256) void binA_kernel(const int* __restrict__ ei,
                                                   const float* __restrict__ ea,
                                                   int* __restrict__ gcur,
                                                   int2* __restrict__ coarse) {
    __shared__ int hist[NBINS], curl[NBINS], basel[NBINS];
    int tid = threadIdx.x;
    for (int b = tid; b < NBINS; b += 256) { hist[b] = 0; curl[b] = 0; }
    __syncthreads();
    int e0 = blockIdx.x * ACHUNK;
    for (int i = tid; i < ACHUNK; i += 256) {            // phase 1: histogram
        int d = ei[NE + e0 + i];
        atomicAdd(&hist[d >> BINSHIFT], 1);
    }
    __syncthreads();
    for (int b = tid; b < NBINS; b += 256)               // phase 2: reserve ranges
        basel[b] = atomicAdd(&gcur[b], hist[b]);
    __syncthreads();
    for (int i = tid; i < ACHUNK; i += 256) {            // phase 3: scatter records
        int e = e0 + i;
        int s = ei[e];
        int d = ei[NE + e];
        float a = ea[e];
        int b = d >> BINSHIFT;
        int p = atomicAdd(&curl[b], 1) + basel[b];
        if (p < BINCAP)
            coarse[(size_t)b * BINCAP + p] = make_int2(s | ((d & 127) << 16),
                                                       __float_as_int(a));
    }
}

// ---------------- STEP B: per-bin fine placement, LDS atomics only.
// Also writes cur[node] (degree) -> no global memset of cur needed.
__global__ __launch_bounds__(256) void binB_kernel(const int* __restrict__ gcur,
                                                   const int2* __restrict__ coarse,
                                                   int* __restrict__ cur,
                                                   int2* __restrict__ slot2) {
    __shared__ int curl[128];
    int b = blockIdx.x, tid = threadIdx.x;
    if (tid < 128) curl[tid] = 0;
    __syncthreads();
    int n = gcur[b]; n = n < BINCAP ? n : BINCAP;
    for (int i = tid; i < n; i += 256) {
        int2 rec = coarse[(size_t)b * BINCAP + i];
        int s = rec.x & 0xFFFF;
        int dl = (rec.x >> 16) & 127;
        int p = atomicAdd(&curl[dl], 1);
        if (p < CAP) slot2[((size_t)((b << BINSHIFT) + dl)) * CAP + p] = make_int2(s, rec.y);
    }
    __syncthreads();
    if (tid < 128) {
        int node = (b << BINSHIFT) + tid;
        if (node < NN) cur[node] = curl[tid];
    }
}

// pack weights into per-lane-contiguous MFMA B-fragment layout:
// Gp[((kk*8+n16)*64+l)*8+j] = G[kk*32+(l>>4)*8+j][n16*16+(l&15)]
__global__ __launch_bounds__(256) void prepw_kernel(const float* __restrict__ W1,
                                                    const float* __restrict__ b1,
                                                    const float* __restrict__ W2,
                                                    ushort* __restrict__ G1p,
                                                    ushort* __restrict__ G2p) {
    int id = blockIdx.x * 256 + threadIdx.x;
    if (id < 20480) {                 // G1: 160x128 (W1 129 rows + b1 + zero pad)
        int j = id & 7, l = (id >> 3) & 63, t = id >> 9;
        int kk = t >> 3, n16 = t & 7;
        int k = kk * 32 + ((l >> 4) * 8) + j, n = n16 * 16 + (l & 15);
        float v = (k < 129) ? W1[k * 128 + n] : ((k == 129) ? b1[n] : 0.f);
        G1p[id] = f2bf(v);
    } else if (id < 20480 + 16384) {  // G2: 128x128 = [W2i | W2j]
        int id2 = id - 20480;
        int j = id2 & 7, l = (id2 >> 3) & 63, t = id2 >> 9;
        int kk = t >> 3, n16 = t & 7;
        int k = kk * 32 + ((l >> 4) * 8) + j, n = n16 * 16 + (l & 15);
        float v = (n < 64) ? W2[k * 64 + n] : W2[(128 + k) * 64 + (n - 64)];
        G2p[id2] = f2bf(v);
    }
}

// -------------------------------------------------- layer-1 gather -> F1b
// F1b row (bf16, stride 160): [0:64)=(deg+1)*x, [64:128)=x+sum_nb, [128]=sea,
// [129]=deg+1, [130:160)=0. Also writes seaf[node] (f32) for final_kernel.
__global__ __launch_bounds__(256) void agg1_kernel(const float* __restrict__ x,
                                                   const ushort* __restrict__ xh,
                                                   const int* __restrict__ cur,
                                                   const int2* __restrict__ slot2,
                                                   ushort* __restrict__ F1b,
                                                   float* __restrict__ seaf) {
    __shared__ int sIdx[4][64];
    int wid2 = threadIdx.x >> 6;
    int node = blockIdx.x * 4 + wid2;
    int c = threadIdx.x & 63;
    ushort* row = F1b + (size_t)node * 160;
    if (node >= NN) {                 // zero pad rows (avoid garbage in MFMA)
        row[c] = 0; row[64 + c] = 0; if (c < 32) row[128 + c] = 0;
        return;
    }
    int cnt = cur[node]; cnt = cnt < CAP ? cnt : CAP;
    // coalesced neighbor {index, ea} for this node
    int2 se = (c < cnt) ? slot2[node * CAP + c] : make_int2(0, 0);
    float eav = (c < cnt) ? __int_as_float(se.y) : 0.f;
    sIdx[wid2][c] = (c < cnt) ? se.x : 0;
#pragma unroll
    for (int o = 1; o < 64; o <<= 1) eav += __shfl_xor(eav, o);   // sea (all lanes)
    float xv = x[node * 64 + c];
    float acc = xv;                   // self loop
    int j = 0;
    for (; j + 8 <= cnt; j += 8) {
        int s0 = sIdx[wid2][j + 0], s1 = sIdx[wid2][j + 1];
        int s2 = sIdx[wid2][j + 2], s3 = sIdx[wid2][j + 3];
        int s4 = sIdx[wid2][j + 4], s5 = sIdx[wid2][j + 5];
        int s6 = sIdx[wid2][j + 6], s7 = sIdx[wid2][j + 7];
        float a0 = bf2f(xh[s0 * 64 + c]), a1 = bf2f(xh[s1 * 64 + c]);
        float a2 = bf2f(xh[s2 * 64 + c]), a3 = bf2f(xh[s3 * 64 + c]);
        float a4 = bf2f(xh[s4 * 64 + c]), a5 = bf2f(xh[s5 * 64 + c]);
        float a6 = bf2f(xh[s6 * 64 + c]), a7 = bf2f(xh[s7 * 64 + c]);
        acc += ((a0 + a1) + (a2 + a3)) + ((a4 + a5) + (a6 + a7));
    }
    for (; j < cnt; ++j) {
        int s = sIdx[wid2][j];
        acc += bf2f(xh[s * 64 + c]);
    }
    float degp = (float)(cnt + 1);
    row[c] = f2bf(degp * xv);
    row[64 + c] = f2bf(acc);
    if (c < 32) {
        ushort z = 0;
        if (c == 0) z = f2bf(eav);
        else if (c == 1) z = f2bf(degp);
        row[128 + c] = z;
    }
    if (c == 0) seaf[node] = eav;
}

// -------------------------------------------------- GEMM1: h = relu(F1b @ G1)
__global__ __launch_bounds__(256) void gemm1_kernel(const ushort* __restrict__ F1b,
                                                    const bf16x8* __restrict__ G1p,
                                                    ushort* __restrict__ h) {
    int w = threadIdx.x >> 6, lane = threadIdx.x & 63;
    int node0 = blockIdx.x * 64;
    int ar = lane & 15, ak = (lane >> 4) * 8;
    f32x4 z = {0.f, 0.f, 0.f, 0.f};
    f32x4 acc[4][2];
#pragma unroll
    for (int mr = 0; mr < 4; ++mr) { acc[mr][0] = z; acc[mr][1] = z; }
#pragma unroll
    for (int kk = 0; kk < 5; ++kk) {
        bf16x8 b0 = G1p[(kk * 8 + w * 2 + 0) * 64 + lane];
        bf16x8 b1 = G1p[(kk * 8 + w * 2 + 1) * 64 + lane];
#pragma unroll
        for (int mr = 0; mr < 4; ++mr) {
            bf16x8 a = *(const bf16x8*)(F1b + (size_t)(node0 + mr * 16 + ar) * 160 + kk * 32 + ak);
            acc[mr][0] = __builtin_amdgcn_mfma_f32_16x16x32_bf16(a, b0, acc[mr][0], 0, 0, 0);
            acc[mr][1] = __builtin_amdgcn_mfma_f32_16x16x32_bf16(a, b1, acc[mr][1], 0, 0, 0);
        }
    }
    int crow = (lane >> 4) * 4, ccol = lane & 15;
#pragma unroll
    for (int mr = 0; mr < 4; ++mr)
#pragma unroll
        for (int nc = 0; nc < 2; ++nc)
#pragma unroll
            for (int r = 0; r < 4; ++r) {
                int row = node0 + mr * 16 + crow + r;   // write ALL NNP rows:
                int col = w * 32 + nc * 16 + ccol;      // replays must never read poison
                h[(size_t)row * 128 + col] = f2bf(fmaxf(acc[mr][nc][r], 0.f));
            }
}

// -------------------------------------- GEMM2: [P2|Q2] = h @ [W2i|W2j]
__global__ __launch_bounds__(256) void gemm2_kernel(const ushort* __restrict__ hb,
                                                    const bf16x8* __restrict__ G2p,
                                                    float* __restrict__ P2,
                                                    ushort* __restrict__ Q2) {
    int w = threadIdx.x >> 6, lane = threadIdx.x & 63;
    int node0 = blockIdx.x * 64;
    int ar = lane & 15, ak = (lane >> 4) * 8;
    f32x4 z = {0.f, 0.f, 0.f, 0.f};
    f32x4 acc[4][2];
#pragma unroll
    for (int mr = 0; mr < 4; ++mr) { acc[mr][0] = z; acc[mr][1] = z; }
#pragma unroll
    for (int kk = 0; kk < 4; ++kk) {
        bf16x8 b0 = G2p[(kk * 8 + w * 2 + 0) * 64 + lane];
        bf16x8 b1 = G2p[(kk * 8 + w * 2 + 1) * 64 + lane];
#pragma unroll
        for (int mr = 0; mr < 4; ++mr) {
            bf16x8 a = *(const bf16x8*)(hb + (size_t)(node0 + mr * 16 + ar) * 128 + kk * 32 + ak);
            acc[mr][0] = __builtin_amdgcn_mfma_f32_16x16x32_bf16(a, b0, acc[mr][0], 0, 0, 0);
            acc[mr][1] = __builtin_amdgcn_mfma_f32_16x16x32_bf16(a, b1, acc[mr][1], 0, 0, 0);
        }
    }
    int crow = (lane >> 4) * 4, ccol = lane & 15;
#pragma unroll
    for (int mr = 0; mr < 4; ++mr)
#pragma unroll
        for (int nc = 0; nc < 2; ++nc)
#pragma unroll
            for (int r = 0; r < 4; ++r) {
                int row = node0 + mr * 16 + crow + r;
                int col = w * 32 + nc * 16 + ccol;   // wave-uniform branch
                if (col < 64) P2[(size_t)row * 64 + col] = acc[mr][nc][r];
                else          Q2[(size_t)row * 64 + (col - 64)] = f2bf(acc[mr][nc][r]);
            }
}

// ---------------------- final: gather Q2, combine, relu, log_softmax
__global__ __launch_bounds__(256) void final_kernel(const float* __restrict__ P2,
                                                    const ushort* __restrict__ Q2,
                                                    const int* __restrict__ cur,
                                                    const int2* __restrict__ slot2,
                                                    const float* __restrict__ seaf,
                                                    const float* __restrict__ W2,
                                                    const float* __restrict__ b2,
                                                    float* __restrict__ out) {
    __shared__ int sIdx[4][64];
    int wid2 = threadIdx.x >> 6;
    int node = blockIdx.x * 4 + wid2;
    int c = threadIdx.x & 63;
    int cnt = cur[node]; cnt = cnt < CAP ? cnt : CAP;
    sIdx[wid2][c] = (c < cnt) ? slot2[node * CAP + c].x : 0;   // coalesced indices
    float acc = bf2f(Q2[(size_t)node * 64 + c]);               // self loop
    int j = 0;
    for (; j + 8 <= cnt; j += 8) {
        int s0 = sIdx[wid2][j + 0], s1 = sIdx[wid2][j + 1];
        int s2 = sIdx[wid2][j + 2], s3 = sIdx[wid2][j + 3];
        int s4 = sIdx[wid2][j + 4], s5 = sIdx[wid2][j + 5];
        int s6 = sIdx[wid2][j + 6], s7 = sIdx[wid2][j + 7];
        float a0 = bf2f(Q2[(size_t)s0 * 64 + c]), a1 = bf2f(Q2[(size_t)s1 * 64 + c]);
        float a2 = bf2f(Q2[(size_t)s2 * 64 + c]), a3 = bf2f(Q2[(size_t)s3 * 64 + c]);
        float a4 = bf2f(Q2[(size_t)s4 * 64 + c]), a5 = bf2f(Q2[(size_t)s5 * 64 + c]);
        float a6 = bf2f(Q2[(size_t)s6 * 64 + c]), a7 = bf2f(Q2[(size_t)s7 * 64 + c]);
        acc += ((a0 + a1) + (a2 + a3)) + ((a4 + a5) + (a6 + a7));
    }
    for (; j < cnt; ++j) {
        int s = sIdx[wid2][j];
        acc += bf2f(Q2[(size_t)s * 64 + c]);
    }
    float degp = (float)(cnt + 1);
    float v = degp * P2[(size_t)node * 64 + c] + acc
            + seaf[node] * W2[256 * 64 + c] + degp * b2[c];
    v = fmaxf(v, 0.f);
    float m = v;
#pragma unroll
    for (int o = 1; o < 64; o <<= 1) m = fmaxf(m, __shfl_xor(m, o));
    float s2 = __expf(v - m);
#pragma unroll
    for (int o = 1; o < 64; o <<= 1) s2 += __shfl_xor(s2, o);
    out[(size_t)node * 64 + c] = v - m - __logf(s2);
}

// ---------------------------------------------------------------- launcher
extern "C" void kernel_launch(void* const* d_in, const int* in_sizes, int n_in,
                              void* d_out, int out_size, void* d_ws, size_t ws_size,
                              hipStream_t stream) {
    const float* x  = (const float*)d_in[0];
    const int*   ei = (const int*)d_in[1];
    const float* ea = (const float*)d_in[2];
    const float* W1 = (const float*)d_in[3];
    const float* b1 = (const float*)d_in[4];
    const float* W2 = (const float*)d_in[5];
    const float* b2 = (const float*)d_in[6];
    float* out = (float*)d_out;

    char* ws = (char*)d_ws;
    size_t off_b = 0;
    auto take = [&](size_t bytes) -> void* {
        void* p = ws + off_b;
        off_b += (bytes + 255) & ~(size_t)255;
        return p;
    };
    int*    gcur   = (int*)take((size_t)NBINS * 4);     // zeroed by prepx_kernel
    int2*   coarse = (int2*)take((size_t)NBINS * BINCAP * 8);
    int*    cur    = (int*)take((size_t)NN * 4);        // fully written by binB
    int2*   slot2  = (int2*)take((size_t)NN * CAP * 8);
    float*  seaf   = (float*)take((size_t)NN * 4);
    ushort* xh     = (ushort*)take((size_t)NN * 64 * 2);
    ushort* F1b    = (ushort*)take((size_t)NNP * 160 * 2);
    ushort* h      = (ushort*)take((size_t)NNP * 128 * 2);
    float*  P2     = (float*)take((size_t)NNP * 64 * 4);
    ushort* Q2     = (ushort*)take((size_t)NNP * 64 * 2);
    ushort* G1p    = (ushort*)take(20480 * 2);
    ushort* G2p    = (ushort*)take(16384 * 2);
    (void)in_sizes; (void)n_in; (void)out_size; (void)ws_size;

    prepx_kernel<<<3125, 256, 0, stream>>>(x, xh, gcur);   // also zeroes gcur
    prepw_kernel<<<144, 256, 0, stream>>>(W1, b1, W2, G1p, G2p);
    binA_kernel<<<NBLK_A, 256, 0, stream>>>(ei, ea, gcur, coarse);
    binB_kernel<<<NBLK_B, 256, 0, stream>>>(gcur, coarse, cur, slot2);
    agg1_kernel<<<NNP / 4, 256, 0, stream>>>(x, xh, cur, slot2, F1b, seaf);
    gemm1_kernel<<<NNP / 64, 256, 0, stream>>>(F1b, (const bf16x8*)G1p, h);
    gemm2_kernel<<<NNP / 64, 256, 0, stream>>>(h, (const bf16x8*)G2p, P2, Q2);
    final_kernel<<<NN / 4, 256, 0, stream>>>(P2, Q2, cur, slot2, seaf, W2, b2, out);
}

// Round 9
// 115.425 us; speedup vs baseline: 1.3268x; 1.0916x over previous
//
#include <hip/hip_runtime.h>

#define NN 50000
#define NNP 50048          // NN padded to multiple of 64
#define NE 800000
#define CAP 64             // per-node neighbor capacity (P(deg>64) ~ 2e-18 at lambda=16)

#define NBINS 512          // coarse bins by dst>>7 (bins 391..511 empty)
#define BINSHIFT 7
#define BINCAP 2560        // max edges/bin: lambda ~2046, +11 sigma
#define ACHUNK 6400        // edges per binA block: 125 * 6400 = 800000 exactly
#define NBLK_A 125
#define NBLK_B 391         // (NN + 127) >> 7

typedef float f32x4 __attribute__((ext_vector_type(4)));
typedef short bf16x8 __attribute__((ext_vector_type(8)));

__device__ __forceinline__ float bf2f(unsigned short u) {
    union { float f; unsigned int i; } v; v.i = ((unsigned int)u) << 16; return v.f;
}
__device__ __forceinline__ unsigned short f2bf(float f) {
    unsigned int i = __float_as_uint(f);
    unsigned int r = i + 0x7FFFu + ((i >> 16) & 1u);
    return (unsigned short)(r >> 16);
}

// ------------------- prep: xh=bf16(x) | pack G1p/G2p | zero gcur (fused)
__global__ __launch_bounds__(256) void prep_kernel(const float* __restrict__ x,
                                                   ushort* __restrict__ xh,
                                                   const float* __restrict__ W1,
                                                   const float* __restrict__ b1,
                                                   const float* __restrict__ W2,
                                                   ushort* __restrict__ G1p,
                                                   ushort* __restrict__ G2p,
                                                   int* __restrict__ gcur) {
    if (blockIdx.x < 3125) {              // 800000 float4 groups of x
        int i = blockIdx.x * 256 + threadIdx.x;
        float4 v = ((const float4*)x)[i];
        ushort4 o;
        o.x = f2bf(v.x); o.y = f2bf(v.y); o.z = f2bf(v.z); o.w = f2bf(v.w);
        ((ushort4*)xh)[i] = o;
        return;
    }
    int wb = blockIdx.x - 3125;           // 145 weight-pack blocks
    if (wb == 0 && threadIdx.x < NBINS / 4)
        ((int4*)gcur)[threadIdx.x] = make_int4(0, 0, 0, 0);
    int id = wb * 256 + threadIdx.x;
    if (id < 20480) {                     // G1: 160x128 (W1 129 rows + b1 + pad)
        int j = id & 7, l = (id >> 3) & 63, t = id >> 9;
        int kk = t >> 3, n16 = t & 7;
        int k = kk * 32 + ((l >> 4) * 8) + j, n = n16 * 16 + (l & 15);
        float v = (k < 129) ? W1[k * 128 + n] : ((k == 129) ? b1[n] : 0.f);
        G1p[id] = f2bf(v);
    } else if (id < 20480 + 16384) {      // G2: 128x128 = [W2i | W2j]
        int id2 = id - 20480;
        int j = id2 & 7, l = (id2 >> 3) & 63, t = id2 >> 9;
        int kk = t >> 3, n16 = t & 7;
        int k = kk * 32 + ((l >> 4) * 8) + j, n = n16 * 16 + (l & 15);
        float v = (n < 64) ? W2[k * 64 + n] : W2[(128 + k) * 64 + (n - 64)];
        G2p[id2] = f2bf(v);
    }
}

// ---------------- STEP A: coarse partition by dst>>7, LDS histogram,
// one global atomic per (block,bin) instead of one per edge.
__global__ __launch_bounds__(256) void binA_kernel(const int* __restrict__ ei,
                                                   const float* __restrict__ ea,
                                                   int* __restrict__ gcur,
                                                   int2* __restrict__ coarse) {
    __shared__ int hist[NBINS], curl[NBINS], basel[NBINS];
    int tid = threadIdx.x;
    for (int b = tid; b < NBINS; b += 256) { hist[b] = 0; curl[b] = 0; }
    __syncthreads();
    int e0 = blockIdx.x * ACHUNK;
    for (int i = tid; i < ACHUNK; i += 256) {            // phase 1: histogram
        int d = ei[NE + e0 + i];
        atomicAdd(&hist[d >> BINSHIFT], 1);
    }
    __syncthreads();
    for (int b = tid; b < NBINS; b += 256)               // phase 2: reserve ranges
        basel[b] = atomicAdd(&gcur[b], hist[b]);
    __syncthreads();
    for (int i = tid; i < ACHUNK; i += 256) {            // phase 3: scatter records
        int e = e0 + i;
        int s = ei[e];
        int d = ei[NE + e];
        float a = ea[e];
        int b = d >> BINSHIFT;
        int p = atomicAdd(&curl[b], 1) + basel[b];
        if (p < BINCAP)
            coarse[(size_t)b * BINCAP + p] = make_int2(s | ((d & 127) << 16),
                                                       __float_as_int(a));
    }
}

// ---------------- STEP B: per-bin fine placement, LDS atomics only.
// Writes cur[node], seaf[node] (sum of edge_attr), and int slot lists.
__global__ __launch_bounds__(256) void binB_kernel(const int* __restrict__ gcur,
                                                   const int2* __restrict__ coarse,
                                                   int* __restrict__ cur,
                                                   float* __restrict__ seaf,
                                                   int* __restrict__ slot) {
    __shared__ int curl[128];
    __shared__ float seal[128];
    int b = blockIdx.x, tid = threadIdx.x;
    if (tid < 128) { curl[tid] = 0; seal[tid] = 0.f; }
    __syncthreads();
    int n = gcur[b]; n = n < BINCAP ? n : BINCAP;
    for (int i = tid; i < n; i += 256) {
        int2 rec = coarse[(size_t)b * BINCAP + i];
        int s = rec.x & 0xFFFF;
        int dl = (rec.x >> 16) & 127;
        int p = atomicAdd(&curl[dl], 1);
        if (p < CAP) slot[((size_t)((b << BINSHIFT) + dl)) * CAP + p] = s;
        atomicAdd(&seal[dl], __int_as_float(rec.y));
    }
    __syncthreads();
    if (tid < 128) {
        int node = (b << BINSHIFT) + tid;
        if (node < NN) { cur[node] = curl[tid]; seaf[node] = seal[tid]; }
    }
}

// -------------------------------------------------- layer-1 gather -> F1b
// F1b row (bf16, stride 160): [0:64)=(deg+1)*x, [64:128)=x+sum_nb, [128]=sea,
// [129]=deg+1, [130:160)=0.
__global__ __launch_bounds__(256) void agg1_kernel(const float* __restrict__ x,
                                                   const ushort* __restrict__ xh,
                                                   const int* __restrict__ cur,
                                                   const int* __restrict__ slot,
                                                   const float* __restrict__ seaf,
                                                   ushort* __restrict__ F1b) {
    __shared__ int sIdx[4][64];
    int wid2 = threadIdx.x >> 6;
    int node = blockIdx.x * 4 + wid2;
    int c = threadIdx.x & 63;
    ushort* row = F1b + (size_t)node * 160;
    if (node >= NN) {                 // zero pad rows (avoid garbage in MFMA)
        row[c] = 0; row[64 + c] = 0; if (c < 32) row[128 + c] = 0;
        return;
    }
    int cnt = cur[node]; cnt = cnt < CAP ? cnt : CAP;
    sIdx[wid2][c] = (c < cnt) ? slot[node * CAP + c] : 0;   // coalesced indices
    float xv = x[node * 64 + c];
    float acc = xv;                   // self loop
    int j = 0;
    for (; j + 8 <= cnt; j += 8) {
        int s0 = sIdx[wid2][j + 0], s1 = sIdx[wid2][j + 1];
        int s2 = sIdx[wid2][j + 2], s3 = sIdx[wid2][j + 3];
        int s4 = sIdx[wid2][j + 4], s5 = sIdx[wid2][j + 5];
        int s6 = sIdx[wid2][j + 6], s7 = sIdx[wid2][j + 7];
        float a0 = bf2f(xh[s0 * 64 + c]), a1 = bf2f(xh[s1 * 64 + c]);
        float a2 = bf2f(xh[s2 * 64 + c]), a3 = bf2f(xh[s3 * 64 + c]);
        float a4 = bf2f(xh[s4 * 64 + c]), a5 = bf2f(xh[s5 * 64 + c]);
        float a6 = bf2f(xh[s6 * 64 + c]), a7 = bf2f(xh[s7 * 64 + c]);
        acc += ((a0 + a1) + (a2 + a3)) + ((a4 + a5) + (a6 + a7));
    }
    for (; j < cnt; ++j) {
        int s = sIdx[wid2][j];
        acc += bf2f(xh[s * 64 + c]);
    }
    float degp = (float)(cnt + 1);
    row[c] = f2bf(degp * xv);
    row[64 + c] = f2bf(acc);
    if (c < 32) {
        ushort z = 0;
        if (c == 0) z = f2bf(seaf[node]);
        else if (c == 1) z = f2bf(degp);
        row[128 + c] = z;
    }
}

// ---------------- fused GEMM: h = relu(F1b@G1) (LDS only), [P2|Q2] = h@G2
// h tile lives in XOR-swizzled LDS: elem (row,col) -> row*128 + ((col>>3)^(row&7))*8 + (col&7)
__global__ __launch_bounds__(256) void gemmF_kernel(const ushort* __restrict__ F1b,
                                                    const bf16x8* __restrict__ G1p,
                                                    const bf16x8* __restrict__ G2p,
                                                    float* __restrict__ P2,
                                                    ushort* __restrict__ Q2) {
    __shared__ ushort hs[64 * 128];       // 16 KB swizzled h tile
    int w = threadIdx.x >> 6, lane = threadIdx.x & 63;
    int node0 = blockIdx.x * 64;
    int ar = lane & 15, ak = (lane >> 4) * 8;
    f32x4 z = {0.f, 0.f, 0.f, 0.f};
    f32x4 acc[4][2];
#pragma unroll
    for (int mr = 0; mr < 4; ++mr) { acc[mr][0] = z; acc[mr][1] = z; }
#pragma unroll
    for (int kk = 0; kk < 5; ++kk) {
        bf16x8 b0 = G1p[(kk * 8 + w * 2 + 0) * 64 + lane];
        bf16x8 b1 = G1p[(kk * 8 + w * 2 + 1) * 64 + lane];
#pragma unroll
        for (int mr = 0; mr < 4; ++mr) {
            bf16x8 a = *(const bf16x8*)(F1b + (size_t)(node0 + mr * 16 + ar) * 160 + kk * 32 + ak);
            acc[mr][0] = __builtin_amdgcn_mfma_f32_16x16x32_bf16(a, b0, acc[mr][0], 0, 0, 0);
            acc[mr][1] = __builtin_amdgcn_mfma_f32_16x16x32_bf16(a, b1, acc[mr][1], 0, 0, 0);
        }
    }
    int crow = (lane >> 4) * 4, ccol = lane & 15;
#pragma unroll
    for (int mr = 0; mr < 4; ++mr)
#pragma unroll
        for (int nc = 0; nc < 2; ++nc)
#pragma unroll
            for (int r = 0; r < 4; ++r) {
                int row = mr * 16 + crow + r;              // 0..63 within tile
                int col = w * 32 + nc * 16 + ccol;         // 0..127
                hs[row * 128 + ((((col >> 3) ^ (row & 7)) << 3) | (col & 7))]
                    = f2bf(fmaxf(acc[mr][nc][r], 0.f));
            }
    __syncthreads();
    // ---- second GEMM: A rows from swizzled LDS
#pragma unroll
    for (int mr = 0; mr < 4; ++mr) { acc[mr][0] = z; acc[mr][1] = z; }
#pragma unroll
    for (int kk = 0; kk < 4; ++kk) {
        bf16x8 b0 = G2p[(kk * 8 + w * 2 + 0) * 64 + lane];
        bf16x8 b1 = G2p[(kk * 8 + w * 2 + 1) * 64 + lane];
#pragma unroll
        for (int mr = 0; mr < 4; ++mr) {
            int row = mr * 16 + ar;
            int cb = kk * 32 + ak;                          // multiple of 8
            bf16x8 a = *(const bf16x8*)(&hs[row * 128 + ((((cb >> 3) ^ (row & 7)) << 3))]);
            acc[mr][0] = __builtin_amdgcn_mfma_f32_16x16x32_bf16(a, b0, acc[mr][0], 0, 0, 0);
            acc[mr][1] = __builtin_amdgcn_mfma_f32_16x16x32_bf16(a, b1, acc[mr][1], 0, 0, 0);
        }
    }
#pragma unroll
    for (int mr = 0; mr < 4; ++mr)
#pragma unroll
        for (int nc = 0; nc < 2; ++nc)
#pragma unroll
            for (int r = 0; r < 4; ++r) {
                int row = node0 + mr * 16 + crow + r;      // write ALL NNP rows
                int col = w * 32 + nc * 16 + ccol;         // wave-uniform branch
                if (col < 64) P2[(size_t)row * 64 + col] = acc[mr][nc][r];
                else          Q2[(size_t)row * 64 + (col - 64)] = f2bf(acc[mr][nc][r]);
            }
}

// ---------------------- final: gather Q2, combine, relu, log_softmax
__global__ __launch_bounds__(256) void final_kernel(const float* __restrict__ P2,
                                                    const ushort* __restrict__ Q2,
                                                    const int* __restrict__ cur,
                                                    const int* __restrict__ slot,
                                                    const float* __restrict__ seaf,
                                                    const float* __restrict__ W2,
                                                    const float* __restrict__ b2,
                                                    float* __restrict__ out) {
    __shared__ int sIdx[4][64];
    int wid2 = threadIdx.x >> 6;
    int node = blockIdx.x * 4 + wid2;
    int c = threadIdx.x & 63;
    int cnt = cur[node]; cnt = cnt < CAP ? cnt : CAP;
    sIdx[wid2][c] = (c < cnt) ? slot[node * CAP + c] : 0;   // coalesced indices
    float acc = bf2f(Q2[(size_t)node * 64 + c]);            // self loop
    int j = 0;
    for (; j + 8 <= cnt; j += 8) {
        int s0 = sIdx[wid2][j + 0], s1 = sIdx[wid2][j + 1];
        int s2 = sIdx[wid2][j + 2], s3 = sIdx[wid2][j + 3];
        int s4 = sIdx[wid2][j + 4], s5 = sIdx[wid2][j + 5];
        int s6 = sIdx[wid2][j + 6], s7 = sIdx[wid2][j + 7];
        float a0 = bf2f(Q2[(size_t)s0 * 64 + c]), a1 = bf2f(Q2[(size_t)s1 * 64 + c]);
        float a2 = bf2f(Q2[(size_t)s2 * 64 + c]), a3 = bf2f(Q2[(size_t)s3 * 64 + c]);
        float a4 = bf2f(Q2[(size_t)s4 * 64 + c]), a5 = bf2f(Q2[(size_t)s5 * 64 + c]);
        float a6 = bf2f(Q2[(size_t)s6 * 64 + c]), a7 = bf2f(Q2[(size_t)s7 * 64 + c]);
        acc += ((a0 + a1) + (a2 + a3)) + ((a4 + a5) + (a6 + a7));
    }
    for (; j < cnt; ++j) {
        int s = sIdx[wid2][j];
        acc += bf2f(Q2[(size_t)s * 64 + c]);
    }
    float degp = (float)(cnt + 1);
    float v = degp * P2[(size_t)node * 64 + c] + acc
            + seaf[node] * W2[256 * 64 + c] + degp * b2[c];
    v = fmaxf(v, 0.f);
    float m = v;
#pragma unroll
    for (int o = 1; o < 64; o <<= 1) m = fmaxf(m, __shfl_xor(m, o));
    float s2 = __expf(v - m);
#pragma unroll
    for (int o = 1; o < 64; o <<= 1) s2 += __shfl_xor(s2, o);
    out[(size_t)node * 64 + c] = v - m - __logf(s2);
}

// ---------------------------------------------------------------- launcher
extern "C" void kernel_launch(void* const* d_in, const int* in_sizes, int n_in,
                              void* d_out, int out_size, void* d_ws, size_t ws_size,
                              hipStream_t stream) {
    const float* x  = (const float*)d_in[0];
    const int*   ei = (const int*)d_in[1];
    const float* ea = (const float*)d_in[2];
    const float* W1 = (const float*)d_in[3];
    const float* b1 = (const float*)d_in[4];
    const float* W2 = (const float*)d_in[5];
    const float* b2 = (const float*)d_in[6];
    float* out = (float*)d_out;

    char* ws = (char*)d_ws;
    size_t off_b = 0;
    auto take = [&](size_t bytes) -> void* {
        void* p = ws + off_b;
        off_b += (bytes + 255) & ~(size_t)255;
        return p;
    };
    int*    gcur   = (int*)take((size_t)NBINS * 4);     // zeroed by prep_kernel
    int2*   coarse = (int2*)take((size_t)NBINS * BINCAP * 8);
    int*    cur    = (int*)take((size_t)NN * 4);        // fully written by binB
    float*  seaf   = (float*)take((size_t)NN * 4);      // fully written by binB
    int*    slot   = (int*)take((size_t)NN * CAP * 4);
    ushort* xh     = (ushort*)take((size_t)NN * 64 * 2);
    ushort* F1b    = (ushort*)take((size_t)NNP * 160 * 2);
    float*  P2     = (float*)take((size_t)NNP * 64 * 4);
    ushort* Q2     = (ushort*)take((size_t)NNP * 64 * 2);
    ushort* G1p    = (ushort*)take(20480 * 2);
    ushort* G2p    = (ushort*)take(16384 * 2);
    (void)in_sizes; (void)n_in; (void)out_size; (void)ws_size;

    prep_kernel<<<3270, 256, 0, stream>>>(x, xh, W1, b1, W2, G1p, G2p, gcur);
    binA_kernel<<<NBLK_A, 256, 0, stream>>>(ei, ea, gcur, coarse);
    binB_kernel<<<NBLK_B, 256, 0, stream>>>(gcur, coarse, cur, seaf, slot);
    agg1_kernel<<<NNP / 4, 256, 0, stream>>>(x, xh, cur, slot, seaf, F1b);
    gemmF_kernel<<<NNP / 64, 256, 0, stream>>>(F1b, (const bf16x8*)G1p,
                                               (const bf16x8*)G2p, P2, Q2);
    final_kernel<<<NN / 4, 256, 0, stream>>>(P2, Q2, cur, slot, seaf, W2, b2, out);
}

// Round 10
// 112.463 us; speedup vs baseline: 1.3618x; 1.0263x over previous
//
#include <hip/hip_runtime.h>

#define NN 50000
#define NNP 50048          // NN padded to multiple of 64
#define NE 800000
#define CAP 64             // per-node neighbor capacity (P(deg>64) ~ 2e-18 at lambda=16)

#define NBINS 512          // coarse bins by dst>>7 (bins 391..511 empty)
#define BINSHIFT 7
#define BINCAP 2560        // max edges/bin: lambda ~2046, +11 sigma
#define ACHUNK 6400        // edges per binA block: 125 * 6400 = 800000 exactly
#define NBLK_A 125
#define NBLK_B 391         // (NN + 127) >> 7

typedef float f32x4 __attribute__((ext_vector_type(4)));
typedef short bf16x8 __attribute__((ext_vector_type(8)));

__device__ __forceinline__ float bf2f(unsigned int u) {
    union { float f; unsigned int i; } v; v.i = u << 16; return v.f;
}
__device__ __forceinline__ unsigned short f2bf(float f) {
    unsigned int i = __float_as_uint(f);
    unsigned int r = i + 0x7FFFu + ((i >> 16) & 1u);
    return (unsigned short)(r >> 16);
}

// ------------------- prep: xh=bf16(x) | pack G1p/G2p | zero gcur (fused)
__global__ __launch_bounds__(256) void prep_kernel(const float* __restrict__ x,
                                                   ushort* __restrict__ xh,
                                                   const float* __restrict__ W1,
                                                   const float* __restrict__ b1,
                                                   const float* __restrict__ W2,
                                                   ushort* __restrict__ G1p,
                                                   ushort* __restrict__ G2p,
                                                   int* __restrict__ gcur) {
    if (blockIdx.x < 3125) {              // 800000 float4 groups of x
        int i = blockIdx.x * 256 + threadIdx.x;
        float4 v = ((const float4*)x)[i];
        ushort4 o;
        o.x = f2bf(v.x); o.y = f2bf(v.y); o.z = f2bf(v.z); o.w = f2bf(v.w);
        ((ushort4*)xh)[i] = o;
        return;
    }
    int wb = blockIdx.x - 3125;           // 145 weight-pack blocks
    if (wb == 0 && threadIdx.x < NBINS / 4)
        ((int4*)gcur)[threadIdx.x] = make_int4(0, 0, 0, 0);
    int id = wb * 256 + threadIdx.x;
    if (id < 20480) {                     // G1: 160x128 (W1 129 rows + b1 + pad)
        int j = id & 7, l = (id >> 3) & 63, t = id >> 9;
        int kk = t >> 3, n16 = t & 7;
        int k = kk * 32 + ((l >> 4) * 8) + j, n = n16 * 16 + (l & 15);
        float v = (k < 129) ? W1[k * 128 + n] : ((k == 129) ? b1[n] : 0.f);
        G1p[id] = f2bf(v);
    } else if (id < 20480 + 16384) {      // G2: 128x128 = [W2i | W2j]
        int id2 = id - 20480;
        int j = id2 & 7, l = (id2 >> 3) & 63, t = id2 >> 9;
        int kk = t >> 3, n16 = t & 7;
        int k = kk * 32 + ((l >> 4) * 8) + j, n = n16 * 16 + (l & 15);
        float v = (n < 64) ? W2[k * 64 + n] : W2[(128 + k) * 64 + (n - 64)];
        G2p[id2] = f2bf(v);
    }
}

// ---------------- STEP A: coarse partition by dst>>7, LDS histogram,
// one global atomic per (block,bin) instead of one per edge.
__global__ __launch_bounds__(256) void binA_kernel(const int* __restrict__ ei,
                                                   const float* __restrict__ ea,
                                                   int* __restrict__ gcur,
                                                   int2* __restrict__ coarse) {
    __shared__ int hist[NBINS], curl[NBINS], basel[NBINS];
    int tid = threadIdx.x;
    for (int b = tid; b < NBINS; b += 256) { hist[b] = 0; curl[b] = 0; }
    __syncthreads();
    int e0 = blockIdx.x * ACHUNK;
    for (int i = tid; i < ACHUNK; i += 256) {            // phase 1: histogram
        int d = ei[NE + e0 + i];
        atomicAdd(&hist[d >> BINSHIFT], 1);
    }
    __syncthreads();
    for (int b = tid; b < NBINS; b += 256)               // phase 2: reserve ranges
        basel[b] = atomicAdd(&gcur[b], hist[b]);
    __syncthreads();
    for (int i = tid; i < ACHUNK; i += 256) {            // phase 3: scatter records
        int e = e0 + i;
        int s = ei[e];
        int d = ei[NE + e];
        float a = ea[e];
        int b = d >> BINSHIFT;
        int p = atomicAdd(&curl[b], 1) + basel[b];
        if (p < BINCAP)
            coarse[(size_t)b * BINCAP + p] = make_int2(s | ((d & 127) << 16),
                                                       __float_as_int(a));
    }
}

// ---------------- STEP B: per-bin fine placement, LDS atomics only.
// Writes cur[node], seaf[node] (sum of edge_attr), and int slot lists.
__global__ __launch_bounds__(256) void binB_kernel(const int* __restrict__ gcur,
                                                   const int2* __restrict__ coarse,
                                                   int* __restrict__ cur,
                                                   float* __restrict__ seaf,
                                                   int* __restrict__ slot) {
    __shared__ int curl[128];
    __shared__ float seal[128];
    int b = blockIdx.x, tid = threadIdx.x;
    if (tid < 128) { curl[tid] = 0; seal[tid] = 0.f; }
    __syncthreads();
    int n = gcur[b]; n = n < BINCAP ? n : BINCAP;
    for (int i = tid; i < n; i += 256) {
        int2 rec = coarse[(size_t)b * BINCAP + i];
        int s = rec.x & 0xFFFF;
        int dl = (rec.x >> 16) & 127;
        int p = atomicAdd(&curl[dl], 1);
        if (p < CAP) slot[((size_t)((b << BINSHIFT) + dl)) * CAP + p] = s;
        atomicAdd(&seal[dl], __int_as_float(rec.y));
    }
    __syncthreads();
    if (tid < 128) {
        int node = (b << BINSHIFT) + tid;
        if (node < NN) { cur[node] = curl[tid]; seaf[node] = seal[tid]; }
    }
}

// -------------------------------------------------- layer-1 gather -> F1b
// Pair-gather: each 32-lane half loads a different neighbor row; one uint
// (2 bf16 channels) per lane; __shfl_xor(.,32) merges halves at the end.
__global__ __launch_bounds__(256) void agg1_kernel(const float* __restrict__ x,
                                                   const ushort* __restrict__ xh,
                                                   const int* __restrict__ cur,
                                                   const int* __restrict__ slot,
                                                   const float* __restrict__ seaf,
                                                   ushort* __restrict__ F1b) {
    __shared__ int sIdx[4][64];
    int w = threadIdx.x >> 6;
    int node = blockIdx.x * 4 + w;
    int lane = threadIdx.x & 63;
    int half = lane >> 5, cc = lane & 31;
    uint* rowu = (uint*)(F1b + (size_t)node * 160);
    if (node >= NN) {                 // zero pad rows (avoid garbage in MFMA)
        rowu[half * 32 + cc] = 0;     // [0:128) ushorts
        if (lane < 16) rowu[64 + lane] = 0;   // [128:160)
        return;
    }
    int cnt = cur[node]; cnt = cnt < CAP ? cnt : CAP;
    sIdx[w][lane] = (lane < cnt) ? slot[node * CAP + lane] : 0;
    const uint* xh32 = (const uint*)xh;
    float ax = 0.f, ay = 0.f;
    int jp = 0;
    for (; jp + 8 <= cnt; jp += 8) {          // 8 rows, 4 loads/lane
        int r0 = sIdx[w][jp + 0 + half], r1 = sIdx[w][jp + 2 + half];
        int r2 = sIdx[w][jp + 4 + half], r3 = sIdx[w][jp + 6 + half];
        uint u0 = xh32[r0 * 32 + cc], u1 = xh32[r1 * 32 + cc];
        uint u2 = xh32[r2 * 32 + cc], u3 = xh32[r3 * 32 + cc];
        ax += (bf2f(u0 & 0xffff) + bf2f(u1 & 0xffff))
            + (bf2f(u2 & 0xffff) + bf2f(u3 & 0xffff));
        ay += (bf2f(u0 >> 16) + bf2f(u1 >> 16))
            + (bf2f(u2 >> 16) + bf2f(u3 >> 16));
    }
    for (; jp + 2 <= cnt; jp += 2) {          // pair tail
        int r = sIdx[w][jp + half];
        uint u = xh32[r * 32 + cc];
        ax += bf2f(u & 0xffff); ay += bf2f(u >> 16);
    }
    if (jp < cnt && half == 1) {              // odd leftover row (half 1)
        int r = sIdx[w][jp];
        uint u = xh32[r * 32 + cc];
        ax += bf2f(u & 0xffff); ay += bf2f(u >> 16);
    }
    ax += __shfl_xor(ax, 32);                 // merge halves
    ay += __shfl_xor(ay, 32);
    float2 xv = ((const float2*)x)[node * 32 + cc];
    float degp = (float)(cnt + 1);
    if (half == 0) {                          // sum segment [64:128): + self
        uint o = (uint)f2bf(ax + xv.x) | ((uint)f2bf(ay + xv.y) << 16);
        rowu[32 + cc] = o;
    } else {                                  // scaled-self segment [0:64)
        uint o = (uint)f2bf(degp * xv.x) | ((uint)f2bf(degp * xv.y) << 16);
        rowu[cc] = o;
    }
    if (lane < 32) {
        ushort z = 0;
        if (lane == 0) z = f2bf(seaf[node]);
        else if (lane == 1) z = f2bf(degp);
        ((ushort*)rowu)[128 + lane] = z;
    }
}

// ---------------- fused GEMM: h = relu(F1b@G1) (LDS only), [P2|Q2] = h@G2
// h tile lives in XOR-swizzled LDS: elem (row,col) -> row*128 + ((col>>3)^(row&7))*8 + (col&7)
__global__ __launch_bounds__(256) void gemmF_kernel(const ushort* __restrict__ F1b,
                                                    const bf16x8* __restrict__ G1p,
                                                    const bf16x8* __restrict__ G2p,
                                                    float* __restrict__ P2,
                                                    ushort* __restrict__ Q2) {
    __shared__ ushort hs[64 * 128];       // 16 KB swizzled h tile
    int w = threadIdx.x >> 6, lane = threadIdx.x & 63;
    int node0 = blockIdx.x * 64;
    int ar = lane & 15, ak = (lane >> 4) * 8;
    f32x4 z = {0.f, 0.f, 0.f, 0.f};
    f32x4 acc[4][2];
#pragma unroll
    for (int mr = 0; mr < 4; ++mr) { acc[mr][0] = z; acc[mr][1] = z; }
#pragma unroll
    for (int kk = 0; kk < 5; ++kk) {
        bf16x8 b0 = G1p[(kk * 8 + w * 2 + 0) * 64 + lane];
        bf16x8 b1 = G1p[(kk * 8 + w * 2 + 1) * 64 + lane];
#pragma unroll
        for (int mr = 0; mr < 4; ++mr) {
            bf16x8 a = *(const bf16x8*)(F1b + (size_t)(node0 + mr * 16 + ar) * 160 + kk * 32 + ak);
            acc[mr][0] = __builtin_amdgcn_mfma_f32_16x16x32_bf16(a, b0, acc[mr][0], 0, 0, 0);
            acc[mr][1] = __builtin_amdgcn_mfma_f32_16x16x32_bf16(a, b1, acc[mr][1], 0, 0, 0);
        }
    }
    int crow = (lane >> 4) * 4, ccol = lane & 15;
#pragma unroll
    for (int mr = 0; mr < 4; ++mr)
#pragma unroll
        for (int nc = 0; nc < 2; ++nc)
#pragma unroll
            for (int r = 0; r < 4; ++r) {
                int row = mr * 16 + crow + r;              // 0..63 within tile
                int col = w * 32 + nc * 16 + ccol;         // 0..127
                hs[row * 128 + ((((col >> 3) ^ (row & 7)) << 3) | (col & 7))]
                    = f2bf(fmaxf(acc[mr][nc][r], 0.f));
            }
    __syncthreads();
    // ---- second GEMM: A rows from swizzled LDS
#pragma unroll
    for (int mr = 0; mr < 4; ++mr) { acc[mr][0] = z; acc[mr][1] = z; }
#pragma unroll
    for (int kk = 0; kk < 4; ++kk) {
        bf16x8 b0 = G2p[(kk * 8 + w * 2 + 0) * 64 + lane];
        bf16x8 b1 = G2p[(kk * 8 + w * 2 + 1) * 64 + lane];
#pragma unroll
        for (int mr = 0; mr < 4; ++mr) {
            int row = mr * 16 + ar;
            int cb = kk * 32 + ak;                          // multiple of 8
            bf16x8 a = *(const bf16x8*)(&hs[row * 128 + ((((cb >> 3) ^ (row & 7)) << 3))]);
            acc[mr][0] = __builtin_amdgcn_mfma_f32_16x16x32_bf16(a, b0, acc[mr][0], 0, 0, 0);
            acc[mr][1] = __builtin_amdgcn_mfma_f32_16x16x32_bf16(a, b1, acc[mr][1], 0, 0, 0);
        }
    }
#pragma unroll
    for (int mr = 0; mr < 4; ++mr)
#pragma unroll
        for (int nc = 0; nc < 2; ++nc)
#pragma unroll
            for (int r = 0; r < 4; ++r) {
                int row = node0 + mr * 16 + crow + r;      // write ALL NNP rows
                int col = w * 32 + nc * 16 + ccol;         // wave-uniform branch
                if (col < 64) P2[(size_t)row * 64 + col] = acc[mr][nc][r];
                else          Q2[(size_t)row * 64 + (col - 64)] = f2bf(acc[mr][nc][r]);
            }
}

// ---------------------- final: pair-gather Q2, combine, relu, log_softmax
__global__ __launch_bounds__(256) void final_kernel(const float* __restrict__ P2,
                                                    const ushort* __restrict__ Q2,
                                                    const int* __restrict__ cur,
                                                    const int* __restrict__ slot,
                                                    const float* __restrict__ seaf,
                                                    const float* __restrict__ W2,
                                                    const float* __restrict__ b2,
                                                    float* __restrict__ out) {
    __shared__ int sIdx[4][64];
    int w = threadIdx.x >> 6;
    int node = blockIdx.x * 4 + w;
    int lane = threadIdx.x & 63;
    int half = lane >> 5, cc = lane & 31;
    int cnt = cur[node]; cnt = cnt < CAP ? cnt : CAP;
    sIdx[w][lane] = (lane < cnt) ? slot[node * CAP + lane] : 0;
    const uint* q32 = (const uint*)Q2;
    float ax = 0.f, ay = 0.f;
    if (half == 0) {                          // self row (half 0)
        uint u = q32[(size_t)node * 32 + cc];
        ax = bf2f(u & 0xffff); ay = bf2f(u >> 16);
    }
    int jp = 0;
    for (; jp + 8 <= cnt; jp += 8) {          // 8 rows, 4 loads/lane
        int r0 = sIdx[w][jp + 0 + half], r1 = sIdx[w][jp + 2 + half];
        int r2 = sIdx[w][jp + 4 + half], r3 = sIdx[w][jp + 6 + half];
        uint u0 = q32[(size_t)r0 * 32 + cc], u1 = q32[(size_t)r1 * 32 + cc];
        uint u2 = q32[(size_t)r2 * 32 + cc], u3 = q32[(size_t)r3 * 32 + cc];
        ax += (bf2f(u0 & 0xffff) + bf2f(u1 & 0xffff))
            + (bf2f(u2 & 0xffff) + bf2f(u3 & 0xffff));
        ay += (bf2f(u0 >> 16) + bf2f(u1 >> 16))
            + (bf2f(u2 >> 16) + bf2f(u3 >> 16));
    }
    for (; jp + 2 <= cnt; jp += 2) {          // pair tail
        int r = sIdx[w][jp + half];
        uint u = q32[(size_t)r * 32 + cc];
        ax += bf2f(u & 0xffff); ay += bf2f(u >> 16);
    }
    if (jp < cnt && half == 1) {              // odd leftover row (half 1)
        int r = sIdx[w][jp];
        uint u = q32[(size_t)r * 32 + cc];
        ax += bf2f(u & 0xffff); ay += bf2f(u >> 16);
    }
    ax += __shfl_xor(ax, 32);                 // both halves now hold totals
    ay += __shfl_xor(ay, 32);
    float2 p2 = ((const float2*)P2)[(size_t)node * 32 + cc];
    float2 w2 = ((const float2*)(W2 + 256 * 64))[cc];
    float2 bv = ((const float2*)b2)[cc];
    float degp = (float)(cnt + 1);
    float sv = seaf[node];
    float v0 = fmaxf(degp * p2.x + ax + sv * w2.x + degp * bv.x, 0.f);
    float v1 = fmaxf(degp * p2.y + ay + sv * w2.y + degp * bv.y, 0.f);
    float m = (half == 0) ? fmaxf(v0, v1) : -3.4e38f;
#pragma unroll
    for (int o = 1; o < 64; o <<= 1) m = fmaxf(m, __shfl_xor(m, o));
    float s2 = (half == 0) ? (__expf(v0 - m) + __expf(v1 - m)) : 0.f;
#pragma unroll
    for (int o = 1; o < 64; o <<= 1) s2 += __shfl_xor(s2, o);
    float lse = m + __logf(s2);
    if (half == 0)
        ((float2*)out)[(size_t)node * 32 + cc] = make_float2(v0 - lse, v1 - lse);
}

// ---------------------------------------------------------------- launcher
extern "C" void kernel_launch(void* const* d_in, const int* in_sizes, int n_in,
                              void* d_out, int out_size, void* d_ws, size_t ws_size,
                              hipStream_t stream) {
    const float* x  = (const float*)d_in[0];
    const int*   ei = (const int*)d_in[1];
    const float* ea = (const float*)d_in[2];
    const float* W1 = (const float*)d_in[3];
    const float* b1 = (const float*)d_in[4];
    const float* W2 = (const float*)d_in[5];
    const float* b2 = (const float*)d_in[6];
    float* out = (float*)d_out;

    char* ws = (char*)d_ws;
    size_t off_b = 0;
    auto take = [&](size_t bytes) -> void* {
        void* p = ws + off_b;
        off_b += (bytes + 255) & ~(size_t)255;
        return p;
    };
    int*    gcur   = (int*)take((size_t)NBINS * 4);     // zeroed by prep_kernel
    int2*   coarse = (int2*)take((size_t)NBINS * BINCAP * 8);
    int*    cur    = (int*)take((size_t)NN * 4);        // fully written by binB
    float*  seaf   = (float*)take((size_t)NN * 4);      // fully written by binB
    int*    slot   = (int*)take((size_t)NN * CAP * 4);
    ushort* xh     = (ushort*)take((size_t)NN * 64 * 2);
    ushort* F1b    = (ushort*)take((size_t)NNP * 160 * 2);
    float*  P2     = (float*)take((size_t)NNP * 64 * 4);
    ushort* Q2     = (ushort*)take((size_t)NNP * 64 * 2);
    ushort* G1p    = (ushort*)take(20480 * 2);
    ushort* G2p    = (ushort*)take(16384 * 2);
    (void)in_sizes; (void)n_in; (void)out_size; (void)ws_size;

    prep_kernel<<<3270, 256, 0, stream>>>(x, xh, W1, b1, W2, G1p, G2p, gcur);
    binA_kernel<<<NBLK_A, 256, 0, stream>>>(ei, ea, gcur, coarse);
    binB_kernel<<<NBLK_B, 256, 0, stream>>>(gcur, coarse, cur, seaf, slot);
    agg1_kernel<<<NNP / 4, 256, 0, stream>>>(x, xh, cur, slot, seaf, F1b);
    gemmF_kernel<<<NNP / 64, 256, 0, stream>>>(F1b, (const bf16x8*)G1p,
                                               (const bf16x8*)G2p, P2, Q2);
    final_kernel<<<NN / 4, 256, 0, stream>>>(P2, Q2, cur, slot, seaf, W2, b2, out);
}

// Round 11
// 110.038 us; speedup vs baseline: 1.3918x; 1.0220x over previous
//
#include <hip/hip_runtime.h>

#define NN 50000
#define NNP 50048          // NN padded to multiple of 64
#define NE 800000
#define CAP 64             // per-node neighbor capacity (P(deg>64) ~ 2e-18 at lambda=16)

#define NBINS 1024         // coarse bins by dst>>6 (64 nodes/bin)
#define BINSHIFT 6
#define BINCAP 1280        // max records/bin: lambda ~781, +17 sigma
#define GCH 256            // hist/scatter chunks
#define ECHUNK 3125        // NE / GCH
#define NBLK_B 782         // ceil(NNP / 64)

typedef float f32x4 __attribute__((ext_vector_type(4)));
typedef short bf16x8 __attribute__((ext_vector_type(8)));

__device__ __forceinline__ float bf2f(unsigned int u) {
    union { float f; unsigned int i; } v; v.i = u << 16; return v.f;
}
__device__ __forceinline__ unsigned short f2bf(float f) {
    unsigned int i = __float_as_uint(f);
    unsigned int r = i + 0x7FFFu + ((i >> 16) & 1u);
    return (unsigned short)(r >> 16);
}

// --------- prep: xh=bf16(x) | pack G1p/G2p | per-chunk LDS histogram (fused)
__global__ __launch_bounds__(256) void prep_kernel(const float* __restrict__ x,
                                                   ushort* __restrict__ xh,
                                                   const float* __restrict__ W1,
                                                   const float* __restrict__ b1,
                                                   const float* __restrict__ W2,
                                                   ushort* __restrict__ G1p,
                                                   ushort* __restrict__ G2p,
                                                   const int* __restrict__ ei,
                                                   int* __restrict__ gh) {
    __shared__ int hist[NBINS];
    if (blockIdx.x < 3125) {              // 800000 float4 groups of x
        int i = blockIdx.x * 256 + threadIdx.x;
        float4 v = ((const float4*)x)[i];
        ushort4 o;
        o.x = f2bf(v.x); o.y = f2bf(v.y); o.z = f2bf(v.z); o.w = f2bf(v.w);
        ((ushort4*)xh)[i] = o;
        return;
    }
    if (blockIdx.x < 3270) {              // 145 weight-pack blocks
        int id = (blockIdx.x - 3125) * 256 + threadIdx.x;
        if (id < 20480) {                 // G1: 160x128 (W1 129 rows + b1 + pad)
            int j = id & 7, l = (id >> 3) & 63, t = id >> 9;
            int kk = t >> 3, n16 = t & 7;
            int k = kk * 32 + ((l >> 4) * 8) + j, n = n16 * 16 + (l & 15);
            float v = (k < 129) ? W1[k * 128 + n] : ((k == 129) ? b1[n] : 0.f);
            G1p[id] = f2bf(v);
        } else if (id < 20480 + 16384) {  // G2: 128x128 = [W2i | W2j]
            int id2 = id - 20480;
            int j = id2 & 7, l = (id2 >> 3) & 63, t = id2 >> 9;
            int kk = t >> 3, n16 = t & 7;
            int k = kk * 32 + ((l >> 4) * 8) + j, n = n16 * 16 + (l & 15);
            float v = (n < 64) ? W2[k * 64 + n] : W2[(128 + k) * 64 + (n - 64)];
            G2p[id2] = f2bf(v);
        }
        return;
    }
    // ---- histogram chunk g
    int g = blockIdx.x - 3270, tid = threadIdx.x;
    for (int b = tid; b < NBINS; b += 256) hist[b] = 0;
    __syncthreads();
    int e0 = g * ECHUNK;
    for (int i = tid; i < ECHUNK; i += 256)
        atomicAdd(&hist[ei[NE + e0 + i] >> BINSHIFT], 1);
    __syncthreads();
    for (int b = tid; b < NBINS; b += 256) gh[g * NBINS + b] = hist[b];
}

// --------- scan: per-bin exclusive prefix over 256 chunk counts (1 wave/bin)
__global__ __launch_bounds__(64) void scan_kernel(const int* __restrict__ gh,
                                                  int* __restrict__ gbase,
                                                  int* __restrict__ tot) {
    int b = blockIdx.x, l = threadIdx.x;
    int v0 = gh[(l * 4 + 0) * NBINS + b];
    int v1 = gh[(l * 4 + 1) * NBINS + b];
    int v2 = gh[(l * 4 + 2) * NBINS + b];
    int v3 = gh[(l * 4 + 3) * NBINS + b];
    int t = v0 + v1 + v2 + v3;
    int s = t;
#pragma unroll
    for (int o = 1; o < 64; o <<= 1) { int u = __shfl_up(s, o); if (l >= o) s += u; }
    int excl = s - t;
    gbase[(l * 4 + 0) * NBINS + b] = excl;
    gbase[(l * 4 + 1) * NBINS + b] = excl + v0;
    gbase[(l * 4 + 2) * NBINS + b] = excl + v0 + v1;
    gbase[(l * 4 + 3) * NBINS + b] = excl + v0 + v1 + v2;
    if (l == 63) tot[b] = s;
}

// --------- scatter: place records at gbase + within-chunk offset (LDS only)
__global__ __launch_bounds__(256) void scatter_kernel(const int* __restrict__ ei,
                                                      const float* __restrict__ ea,
                                                      const int* __restrict__ gbase,
                                                      int2* __restrict__ coarse) {
    __shared__ int curl[NBINS];
    __shared__ int gb[NBINS];
    int g = blockIdx.x, tid = threadIdx.x;
    for (int b = tid; b < NBINS; b += 256) { curl[b] = 0; gb[b] = gbase[g * NBINS + b]; }
    __syncthreads();
    int e0 = g * ECHUNK;
    for (int i = tid; i < ECHUNK; i += 256) {
        int e = e0 + i;
        int s = ei[e];
        int d = ei[NE + e];
        float a = ea[e];
        int b = d >> BINSHIFT;
        int p = atomicAdd(&curl[b], 1) + gb[b];
        if (p < BINCAP)
            coarse[(size_t)b * BINCAP + p] = make_int2(s | ((d & 63) << 16),
                                                       __float_as_int(a));
    }
}

// --------- binB: per-bin fine placement (64 nodes/bin), LDS atomics only.
__global__ __launch_bounds__(256) void binB_kernel(const int* __restrict__ tot,
                                                   const int2* __restrict__ coarse,
                                                   int* __restrict__ cur,
                                                   float* __restrict__ seaf,
                                                   int* __restrict__ slot) {
    __shared__ int curl[64];
    __shared__ float seal[64];
    int b = blockIdx.x, tid = threadIdx.x;
    if (tid < 64) { curl[tid] = 0; seal[tid] = 0.f; }
    __syncthreads();
    int n = tot[b]; n = n < BINCAP ? n : BINCAP;
    for (int i = tid; i < n; i += 256) {
        int2 rec = coarse[(size_t)b * BINCAP + i];
        int s = rec.x & 0xFFFF;
        int dl = (rec.x >> 16) & 63;
        int p = atomicAdd(&curl[dl], 1);
        if (p < CAP) slot[((size_t)((b << BINSHIFT) + dl)) * CAP + p] = s;
        atomicAdd(&seal[dl], __int_as_float(rec.y));
    }
    __syncthreads();
    if (tid < 64) {
        int node = (b << BINSHIFT) + tid;
        if (node < NN) { cur[node] = curl[tid]; seaf[node] = seal[tid]; }
    }
}

// -------------------------------------------------- layer-1 gather -> F1b
// Pair-gather: each 32-lane half loads a different neighbor row; one uint
// (2 bf16 channels) per lane; __shfl_xor(.,32) merges halves at the end.
__global__ __launch_bounds__(256) void agg1_kernel(const float* __restrict__ x,
                                                   const ushort* __restrict__ xh,
                                                   const int* __restrict__ cur,
                                                   const int* __restrict__ slot,
                                                   const float* __restrict__ seaf,
                                                   ushort* __restrict__ F1b) {
    __shared__ int sIdx[4][64];
    int w = threadIdx.x >> 6;
    int node = blockIdx.x * 4 + w;
    int lane = threadIdx.x & 63;
    int half = lane >> 5, cc = lane & 31;
    uint* rowu = (uint*)(F1b + (size_t)node * 160);
    if (node >= NN) {                 // zero pad rows (avoid garbage in MFMA)
        rowu[half * 32 + cc] = 0;     // [0:128) ushorts
        if (lane < 16) rowu[64 + lane] = 0;   // [128:160)
        return;
    }
    int cnt = cur[node]; cnt = cnt < CAP ? cnt : CAP;
    sIdx[w][lane] = (lane < cnt) ? slot[node * CAP + lane] : 0;
    const uint* xh32 = (const uint*)xh;
    float ax = 0.f, ay = 0.f;
    int jp = 0;
    for (; jp + 8 <= cnt; jp += 8) {          // 8 rows, 4 loads/lane
        int r0 = sIdx[w][jp + 0 + half], r1 = sIdx[w][jp + 2 + half];
        int r2 = sIdx[w][jp + 4 + half], r3 = sIdx[w][jp + 6 + half];
        uint u0 = xh32[r0 * 32 + cc], u1 = xh32[r1 * 32 + cc];
        uint u2 = xh32[r2 * 32 + cc], u3 = xh32[r3 * 32 + cc];
        ax += (bf2f(u0 & 0xffff) + bf2f(u1 & 0xffff))
            + (bf2f(u2 & 0xffff) + bf2f(u3 & 0xffff));
        ay += (bf2f(u0 >> 16) + bf2f(u1 >> 16))
            + (bf2f(u2 >> 16) + bf2f(u3 >> 16));
    }
    for (; jp + 2 <= cnt; jp += 2) {          // pair tail
        int r = sIdx[w][jp + half];
        uint u = xh32[r * 32 + cc];
        ax += bf2f(u & 0xffff); ay += bf2f(u >> 16);
    }
    if (jp < cnt && half == 1) {              // odd leftover row (half 1)
        int r = sIdx[w][jp];
        uint u = xh32[r * 32 + cc];
        ax += bf2f(u & 0xffff); ay += bf2f(u >> 16);
    }
    ax += __shfl_xor(ax, 32);                 // merge halves
    ay += __shfl_xor(ay, 32);
    float2 xv = ((const float2*)x)[node * 32 + cc];
    float degp = (float)(cnt + 1);
    if (half == 0) {                          // sum segment [64:128): + self
        uint o = (uint)f2bf(ax + xv.x) | ((uint)f2bf(ay + xv.y) << 16);
        rowu[32 + cc] = o;
    } else {                                  // scaled-self segment [0:64)
        uint o = (uint)f2bf(degp * xv.x) | ((uint)f2bf(degp * xv.y) << 16);
        rowu[cc] = o;
    }
    if (lane < 32) {
        ushort z = 0;
        if (lane == 0) z = f2bf(seaf[node]);
        else if (lane == 1) z = f2bf(degp);
        ((ushort*)rowu)[128 + lane] = z;
    }
}

// ---------------- fused GEMM: h = relu(F1b@G1) (LDS only), [P2|Q2] = h@G2
// h tile lives in XOR-swizzled LDS: elem (row,col) -> row*128 + ((col>>3)^(row&7))*8 + (col&7)
__global__ __launch_bounds__(256) void gemmF_kernel(const ushort* __restrict__ F1b,
                                                    const bf16x8* __restrict__ G1p,
                                                    const bf16x8* __restrict__ G2p,
                                                    float* __restrict__ P2,
                                                    ushort* __restrict__ Q2) {
    __shared__ ushort hs[64 * 128];       // 16 KB swizzled h tile
    int w = threadIdx.x >> 6, lane = threadIdx.x & 63;
    int node0 = blockIdx.x * 64;
    int ar = lane & 15, ak = (lane >> 4) * 8;
    f32x4 z = {0.f, 0.f, 0.f, 0.f};
    f32x4 acc[4][2];
#pragma unroll
    for (int mr = 0; mr < 4; ++mr) { acc[mr][0] = z; acc[mr][1] = z; }
#pragma unroll
    for (int kk = 0; kk < 5; ++kk) {
        bf16x8 b0 = G1p[(kk * 8 + w * 2 + 0) * 64 + lane];
        bf16x8 b1 = G1p[(kk * 8 + w * 2 + 1) * 64 + lane];
#pragma unroll
        for (int mr = 0; mr < 4; ++mr) {
            bf16x8 a = *(const bf16x8*)(F1b + (size_t)(node0 + mr * 16 + ar) * 160 + kk * 32 + ak);
            acc[mr][0] = __builtin_amdgcn_mfma_f32_16x16x32_bf16(a, b0, acc[mr][0], 0, 0, 0);
            acc[mr][1] = __builtin_amdgcn_mfma_f32_16x16x32_bf16(a, b1, acc[mr][1], 0, 0, 0);
        }
    }
    int crow = (lane >> 4) * 4, ccol = lane & 15;
#pragma unroll
    for (int mr = 0; mr < 4; ++mr)
#pragma unroll
        for (int nc = 0; nc < 2; ++nc)
#pragma unroll
            for (int r = 0; r < 4; ++r) {
                int row = mr * 16 + crow + r;              // 0..63 within tile
                int col = w * 32 + nc * 16 + ccol;         // 0..127
                hs[row * 128 + ((((col >> 3) ^ (row & 7)) << 3) | (col & 7))]
                    = f2bf(fmaxf(acc[mr][nc][r], 0.f));
            }
    __syncthreads();
    // ---- second GEMM: A rows from swizzled LDS
#pragma unroll
    for (int mr = 0; mr < 4; ++mr) { acc[mr][0] = z; acc[mr][1] = z; }
#pragma unroll
    for (int kk = 0; kk < 4; ++kk) {
        bf16x8 b0 = G2p[(kk * 8 + w * 2 + 0) * 64 + lane];
        bf16x8 b1 = G2p[(kk * 8 + w * 2 + 1) * 64 + lane];
#pragma unroll
        for (int mr = 0; mr < 4; ++mr) {
            int row = mr * 16 + ar;
            int cb = kk * 32 + ak;                          // multiple of 8
            bf16x8 a = *(const bf16x8*)(&hs[row * 128 + ((((cb >> 3) ^ (row & 7)) << 3))]);
            acc[mr][0] = __builtin_amdgcn_mfma_f32_16x16x32_bf16(a, b0, acc[mr][0], 0, 0, 0);
            acc[mr][1] = __builtin_amdgcn_mfma_f32_16x16x32_bf16(a, b1, acc[mr][1], 0, 0, 0);
        }
    }
#pragma unroll
    for (int mr = 0; mr < 4; ++mr)
#pragma unroll
        for (int nc = 0; nc < 2; ++nc)
#pragma unroll
            for (int r = 0; r < 4; ++r) {
                int row = node0 + mr * 16 + crow + r;      // write ALL NNP rows
                int col = w * 32 + nc * 16 + ccol;         // wave-uniform branch
                if (col < 64) P2[(size_t)row * 64 + col] = acc[mr][nc][r];
                else          Q2[(size_t)row * 64 + (col - 64)] = f2bf(acc[mr][nc][r]);
            }
}

// ---------------------- final: pair-gather Q2, combine, relu, log_softmax
__global__ __launch_bounds__(256) void final_kernel(const float* __restrict__ P2,
                                                    const ushort* __restrict__ Q2,
                                                    const int* __restrict__ cur,
                                                    const int* __restrict__ slot,
                                                    const float* __restrict__ seaf,
                                                    const float* __restrict__ W2,
                                                    const float* __restrict__ b2,
                                                    float* __restrict__ out) {
    __shared__ int sIdx[4][64];
    int w = threadIdx.x >> 6;
    int node = blockIdx.x * 4 + w;
    int lane = threadIdx.x & 63;
    int half = lane >> 5, cc = lane & 31;
    int cnt = cur[node]; cnt = cnt < CAP ? cnt : CAP;
    sIdx[w][lane] = (lane < cnt) ? slot[node * CAP + lane] : 0;
    const uint* q32 = (const uint*)Q2;
    float ax = 0.f, ay = 0.f;
    if (half == 0) {                          // self row (half 0)
        uint u = q32[(size_t)node * 32 + cc];
        ax = bf2f(u & 0xffff); ay = bf2f(u >> 16);
    }
    int jp = 0;
    for (; jp + 8 <= cnt; jp += 8) {          // 8 rows, 4 loads/lane
        int r0 = sIdx[w][jp + 0 + half], r1 = sIdx[w][jp + 2 + half];
        int r2 = sIdx[w][jp + 4 + half], r3 = sIdx[w][jp + 6 + half];
        uint u0 = q32[(size_t)r0 * 32 + cc], u1 = q32[(size_t)r1 * 32 + cc];
        uint u2 = q32[(size_t)r2 * 32 + cc], u3 = q32[(size_t)r3 * 32 + cc];
        ax += (bf2f(u0 & 0xffff) + bf2f(u1 & 0xffff))
            + (bf2f(u2 & 0xffff) + bf2f(u3 & 0xffff));
        ay += (bf2f(u0 >> 16) + bf2f(u1 >> 16))
            + (bf2f(u2 >> 16) + bf2f(u3 >> 16));
    }
    for (; jp + 2 <= cnt; jp += 2) {          // pair tail
        int r = sIdx[w][jp + half];
        uint u = q32[(size_t)r * 32 + cc];
        ax += bf2f(u & 0xffff); ay += bf2f(u >> 16);
    }
    if (jp < cnt && half == 1) {              // odd leftover row (half 1)
        int r = sIdx[w][jp];
        uint u = q32[(size_t)r * 32 + cc];
        ax += bf2f(u & 0xffff); ay += bf2f(u >> 16);
    }
    ax += __shfl_xor(ax, 32);                 // both halves now hold totals
    ay += __shfl_xor(ay, 32);
    float2 p2 = ((const float2*)P2)[(size_t)node * 32 + cc];
    float2 w2 = ((const float2*)(W2 + 256 * 64))[cc];
    float2 bv = ((const float2*)b2)[cc];
    float degp = (float)(cnt + 1);
    float sv = seaf[node];
    float v0 = fmaxf(degp * p2.x + ax + sv * w2.x + degp * bv.x, 0.f);
    float v1 = fmaxf(degp * p2.y + ay + sv * w2.y + degp * bv.y, 0.f);
    float m = (half == 0) ? fmaxf(v0, v1) : -3.4e38f;
#pragma unroll
    for (int o = 1; o < 64; o <<= 1) m = fmaxf(m, __shfl_xor(m, o));
    float s2 = (half == 0) ? (__expf(v0 - m) + __expf(v1 - m)) : 0.f;
#pragma unroll
    for (int o = 1; o < 64; o <<= 1) s2 += __shfl_xor(s2, o);
    float lse = m + __logf(s2);
    if (half == 0)
        ((float2*)out)[(size_t)node * 32 + cc] = make_float2(v0 - lse, v1 - lse);
}

// ---------------------------------------------------------------- launcher
extern "C" void kernel_launch(void* const* d_in, const int* in_sizes, int n_in,
                              void* d_out, int out_size, void* d_ws, size_t ws_size,
                              hipStream_t stream) {
    const float* x  = (const float*)d_in[0];
    const int*   ei = (const int*)d_in[1];
    const float* ea = (const float*)d_in[2];
    const float* W1 = (const float*)d_in[3];
    const float* b1 = (const float*)d_in[4];
    const float* W2 = (const float*)d_in[5];
    const float* b2 = (const float*)d_in[6];
    float* out = (float*)d_out;

    char* ws = (char*)d_ws;
    size_t off_b = 0;
    auto take = [&](size_t bytes) -> void* {
        void* p = ws + off_b;
        off_b += (bytes + 255) & ~(size_t)255;
        return p;
    };
    int*    gh     = (int*)take((size_t)GCH * NBINS * 4);    // fully written by prep
    int*    gbase  = (int*)take((size_t)GCH * NBINS * 4);    // fully written by scan
    int*    tot    = (int*)take((size_t)NBINS * 4);          // fully written by scan
    int2*   coarse = (int2*)take((size_t)NBINS * BINCAP * 8);
    int*    cur    = (int*)take((size_t)NN * 4);             // fully written by binB
    float*  seaf   = (float*)take((size_t)NN * 4);           // fully written by binB
    int*    slot   = (int*)take((size_t)NNP * CAP * 4);
    ushort* xh     = (ushort*)take((size_t)NN * 64 * 2);
    ushort* F1b    = (ushort*)take((size_t)NNP * 160 * 2);
    float*  P2     = (float*)take((size_t)NNP * 64 * 4);
    ushort* Q2     = (ushort*)take((size_t)NNP * 64 * 2);
    ushort* G1p    = (ushort*)take(20480 * 2);
    ushort* G2p    = (ushort*)take(16384 * 2);
    (void)in_sizes; (void)n_in; (void)out_size; (void)ws_size;

    prep_kernel<<<3270 + GCH, 256, 0, stream>>>(x, xh, W1, b1, W2, G1p, G2p, ei, gh);
    scan_kernel<<<NBINS, 64, 0, stream>>>(gh, gbase, tot);
    scatter_kernel<<<GCH, 256, 0, stream>>>(ei, ea, gbase, coarse);
    binB_kernel<<<NBLK_B, 256, 0, stream>>>(tot, coarse, cur, seaf, slot);
    agg1_kernel<<<NNP / 4, 256, 0, stream>>>(x, xh, cur, slot, seaf, F1b);
    gemmF_kernel<<<NNP / 64, 256, 0, stream>>>(F1b, (const bf16x8*)G1p,
                                               (const bf16x8*)G2p, P2, Q2);
    final_kernel<<<NN / 4, 256, 0, stream>>>(P2, Q2, cur, slot, seaf, W2, b2, out);
}

// Round 12
// 102.610 us; speedup vs baseline: 1.4925x; 1.0724x over previous
//
#include <hip/hip_runtime.h>

#define NN 50000
#define NNP 50048          // NN padded to multiple of 64
#define NE 800000
#define CAP 64             // per-node neighbor capacity (P(deg>64) ~ 2e-18 at lambda=16)

#define NBINS 1024         // coarse bins by dst>>6 (64 nodes/bin)
#define BINSHIFT 6
#define BINCAP 1280        // max records/bin: lambda ~781, +17 sigma
#define GCH 256            // hist/scatter chunks
#define ECHUNK 3125        // NE / GCH
#define NBLK_B 782         // ceil(NNP / 64)

typedef float f32x4 __attribute__((ext_vector_type(4)));
typedef short bf16x8 __attribute__((ext_vector_type(8)));

__device__ __forceinline__ float bf2f(unsigned int u) {
    union { float f; unsigned int i; } v; v.i = u << 16; return v.f;
}
__device__ __forceinline__ unsigned short f2bf(float f) {
    unsigned int i = __float_as_uint(f);
    unsigned int r = i + 0x7FFFu + ((i >> 16) & 1u);
    return (unsigned short)(r >> 16);
}

// --------- prep: xh=bf16(x) (+zero pad rows) | pack G1p/G2p | chunk histograms
__global__ __launch_bounds__(256) void prep_kernel(const float* __restrict__ x,
                                                   ushort* __restrict__ xh,
                                                   const float* __restrict__ W1,
                                                   const float* __restrict__ b1,
                                                   const float* __restrict__ W2,
                                                   ushort* __restrict__ G1p,
                                                   ushort* __restrict__ G2p,
                                                   const int* __restrict__ ei,
                                                   int* __restrict__ gh) {
    __shared__ int hist[NBINS];
    if (blockIdx.x < 3125) {              // 800000 float4 groups of x
        int i = blockIdx.x * 256 + threadIdx.x;
        float4 v = ((const float4*)x)[i];
        ushort4 o;
        o.x = f2bf(v.x); o.y = f2bf(v.y); o.z = f2bf(v.z); o.w = f2bf(v.w);
        ((ushort4*)xh)[i] = o;
        return;
    }
    if (blockIdx.x < 3270) {              // 145 weight-pack blocks
        int wb = blockIdx.x - 3125;
        if (wb == 144) {                  // idle tail block: zero xh pad rows NN..NNP-1
            uint* z = (uint*)(xh + (size_t)NN * 64);
            for (int i = threadIdx.x; i < (NNP - NN) * 32; i += 256) z[i] = 0;
            return;
        }
        int id = wb * 256 + threadIdx.x;
        if (id < 20480) {                 // G1: 160x128 (W1 129 rows + b1 + pad)
            int j = id & 7, l = (id >> 3) & 63, t = id >> 9;
            int kk = t >> 3, n16 = t & 7;
            int k = kk * 32 + ((l >> 4) * 8) + j, n = n16 * 16 + (l & 15);
            float v = (k < 129) ? W1[k * 128 + n] : ((k == 129) ? b1[n] : 0.f);
            G1p[id] = f2bf(v);
        } else if (id < 20480 + 16384) {  // G2: 128x128 = [W2i | W2j]
            int id2 = id - 20480;
            int j = id2 & 7, l = (id2 >> 3) & 63, t = id2 >> 9;
            int kk = t >> 3, n16 = t & 7;
            int k = kk * 32 + ((l >> 4) * 8) + j, n = n16 * 16 + (l & 15);
            float v = (n < 64) ? W2[k * 64 + n] : W2[(128 + k) * 64 + (n - 64)];
            G2p[id2] = f2bf(v);
        }
        return;
    }
    // ---- histogram chunk g
    int g = blockIdx.x - 3270, tid = threadIdx.x;
    for (int b = tid; b < NBINS; b += 256) hist[b] = 0;
    __syncthreads();
    int e0 = g * ECHUNK;
    for (int i = tid; i < ECHUNK; i += 256)
        atomicAdd(&hist[ei[NE + e0 + i] >> BINSHIFT], 1);
    __syncthreads();
    for (int b = tid; b < NBINS; b += 256) gh[g * NBINS + b] = hist[b];
}

// --------- scan: per-bin exclusive prefix over 256 chunk counts (1 wave/bin)
__global__ __launch_bounds__(64) void scan_kernel(const int* __restrict__ gh,
                                                  int* __restrict__ gbase,
                                                  int* __restrict__ tot) {
    int b = blockIdx.x, l = threadIdx.x;
    int v0 = gh[(l * 4 + 0) * NBINS + b];
    int v1 = gh[(l * 4 + 1) * NBINS + b];
    int v2 = gh[(l * 4 + 2) * NBINS + b];
    int v3 = gh[(l * 4 + 3) * NBINS + b];
    int t = v0 + v1 + v2 + v3;
    int s = t;
#pragma unroll
    for (int o = 1; o < 64; o <<= 1) { int u = __shfl_up(s, o); if (l >= o) s += u; }
    int excl = s - t;
    gbase[(l * 4 + 0) * NBINS + b] = excl;
    gbase[(l * 4 + 1) * NBINS + b] = excl + v0;
    gbase[(l * 4 + 2) * NBINS + b] = excl + v0 + v1;
    gbase[(l * 4 + 3) * NBINS + b] = excl + v0 + v1 + v2;
    if (l == 63) tot[b] = s;
}

// --------- scatter: place records at gbase + within-chunk offset (LDS only)
__global__ __launch_bounds__(256) void scatter_kernel(const int* __restrict__ ei,
                                                      const float* __restrict__ ea,
                                                      const int* __restrict__ gbase,
                                                      int2* __restrict__ coarse) {
    __shared__ int curl[NBINS];
    __shared__ int gb[NBINS];
    int g = blockIdx.x, tid = threadIdx.x;
    for (int b = tid; b < NBINS; b += 256) { curl[b] = 0; gb[b] = gbase[g * NBINS + b]; }
    __syncthreads();
    int e0 = g * ECHUNK;
    for (int i = tid; i < ECHUNK; i += 256) {
        int e = e0 + i;
        int s = ei[e];
        int d = ei[NE + e];
        float a = ea[e];
        int b = d >> BINSHIFT;
        int p = atomicAdd(&curl[b], 1) + gb[b];
        if (p < BINCAP)
            coarse[(size_t)b * BINCAP + p] = make_int2(s | ((d & 63) << 16),
                                                       __float_as_int(a));
    }
}

// --------- binB: per-bin fine placement (64 nodes/bin), LDS atomics only.
__global__ __launch_bounds__(256) void binB_kernel(const int* __restrict__ tot,
                                                   const int2* __restrict__ coarse,
                                                   int* __restrict__ cur,
                                                   float* __restrict__ seaf,
                                                   int* __restrict__ slot) {
    __shared__ int curl[64];
    __shared__ float seal[64];
    int b = blockIdx.x, tid = threadIdx.x;
    if (tid < 64) { curl[tid] = 0; seal[tid] = 0.f; }
    __syncthreads();
    int n = tot[b]; n = n < BINCAP ? n : BINCAP;
    for (int i = tid; i < n; i += 256) {
        int2 rec = coarse[(size_t)b * BINCAP + i];
        int s = rec.x & 0xFFFF;
        int dl = (rec.x >> 16) & 63;
        int p = atomicAdd(&curl[dl], 1);
        if (p < CAP) slot[((size_t)((b << BINSHIFT) + dl)) * CAP + p] = s;
        atomicAdd(&seal[dl], __int_as_float(rec.y));
    }
    __syncthreads();
    if (tid < 64) {
        int node = (b << BINSHIFT) + tid;
        if (node < NN) { cur[node] = curl[tid]; seaf[node] = seal[tid]; }
    }
}

// -------------------------------------------------- layer-1 gather -> F1b
// Zero-row padding (index NN) -> full 16-row batches, no serial tail.
__global__ __launch_bounds__(256) void agg1_kernel(const float* __restrict__ x,
                                                   const ushort* __restrict__ xh,
                                                   const int* __restrict__ cur,
                                                   const int* __restrict__ slot,
                                                   const float* __restrict__ seaf,
                                                   ushort* __restrict__ F1b) {
    __shared__ int sIdx[4][64];
    int w = threadIdx.x >> 6;
    int node = blockIdx.x * 4 + w;
    int lane = threadIdx.x & 63;
    int half = lane >> 5, cc = lane & 31;
    uint* rowu = (uint*)(F1b + (size_t)node * 160);
    if (node >= NN) {                 // zero pad rows (avoid garbage in MFMA)
        rowu[half * 32 + cc] = 0;     // [0:128) ushorts
        if (lane < 16) rowu[64 + lane] = 0;   // [128:160)
        return;
    }
    int cnt = cur[node]; cnt = cnt < CAP ? cnt : CAP;
    sIdx[w][lane] = (lane < cnt) ? slot[node * CAP + lane] : NN;  // NN = zero row
    const uint* xh32 = (const uint*)xh;
    float ax = 0.f, ay = 0.f;
    for (int jp = 0; jp < cnt; jp += 16) {    // full 16-row batches, 8 loads/lane
        int r0 = sIdx[w][jp + 0 + half],  r1 = sIdx[w][jp + 2 + half];
        int r2 = sIdx[w][jp + 4 + half],  r3 = sIdx[w][jp + 6 + half];
        int r4 = sIdx[w][jp + 8 + half],  r5 = sIdx[w][jp + 10 + half];
        int r6 = sIdx[w][jp + 12 + half], r7 = sIdx[w][jp + 14 + half];
        uint u0 = xh32[r0 * 32 + cc], u1 = xh32[r1 * 32 + cc];
        uint u2 = xh32[r2 * 32 + cc], u3 = xh32[r3 * 32 + cc];
        uint u4 = xh32[r4 * 32 + cc], u5 = xh32[r5 * 32 + cc];
        uint u6 = xh32[r6 * 32 + cc], u7 = xh32[r7 * 32 + cc];
        ax += ((bf2f(u0 & 0xffff) + bf2f(u1 & 0xffff))
             + (bf2f(u2 & 0xffff) + bf2f(u3 & 0xffff)))
            + ((bf2f(u4 & 0xffff) + bf2f(u5 & 0xffff))
             + (bf2f(u6 & 0xffff) + bf2f(u7 & 0xffff)));
        ay += ((bf2f(u0 >> 16) + bf2f(u1 >> 16))
             + (bf2f(u2 >> 16) + bf2f(u3 >> 16)))
            + ((bf2f(u4 >> 16) + bf2f(u5 >> 16))
             + (bf2f(u6 >> 16) + bf2f(u7 >> 16)));
    }
    ax += __shfl_xor(ax, 32);                 // merge halves
    ay += __shfl_xor(ay, 32);
    float2 xv = ((const float2*)x)[node * 32 + cc];
    float degp = (float)(cnt + 1);
    if (half == 0) {                          // sum segment [64:128): + self
        uint o = (uint)f2bf(ax + xv.x) | ((uint)f2bf(ay + xv.y) << 16);
        rowu[32 + cc] = o;
    } else {                                  // scaled-self segment [0:64)
        uint o = (uint)f2bf(degp * xv.x) | ((uint)f2bf(degp * xv.y) << 16);
        rowu[cc] = o;
    }
    if (lane < 32) {
        ushort z = 0;
        if (lane == 0) z = f2bf(seaf[node]);
        else if (lane == 1) z = f2bf(degp);
        ((ushort*)rowu)[128 + lane] = z;
    }
}

// ---------------- fused GEMM: h = relu(F1b@G1) (LDS only), [P2|Q2] = h@G2
// h tile lives in XOR-swizzled LDS: elem (row,col) -> row*128 + ((col>>3)^(row&7))*8 + (col&7)
__global__ __launch_bounds__(256) void gemmF_kernel(const ushort* __restrict__ F1b,
                                                    const bf16x8* __restrict__ G1p,
                                                    const bf16x8* __restrict__ G2p,
                                                    ushort* __restrict__ P2h,
                                                    ushort* __restrict__ Q2) {
    __shared__ ushort hs[64 * 128];       // 16 KB swizzled h tile
    int w = threadIdx.x >> 6, lane = threadIdx.x & 63;
    int node0 = blockIdx.x * 64;
    int ar = lane & 15, ak = (lane >> 4) * 8;
    f32x4 z = {0.f, 0.f, 0.f, 0.f};
    f32x4 acc[4][2];
#pragma unroll
    for (int mr = 0; mr < 4; ++mr) { acc[mr][0] = z; acc[mr][1] = z; }
#pragma unroll
    for (int kk = 0; kk < 5; ++kk) {
        bf16x8 b0 = G1p[(kk * 8 + w * 2 + 0) * 64 + lane];
        bf16x8 b1 = G1p[(kk * 8 + w * 2 + 1) * 64 + lane];
#pragma unroll
        for (int mr = 0; mr < 4; ++mr) {
            bf16x8 a = *(const bf16x8*)(F1b + (size_t)(node0 + mr * 16 + ar) * 160 + kk * 32 + ak);
            acc[mr][0] = __builtin_amdgcn_mfma_f32_16x16x32_bf16(a, b0, acc[mr][0], 0, 0, 0);
            acc[mr][1] = __builtin_amdgcn_mfma_f32_16x16x32_bf16(a, b1, acc[mr][1], 0, 0, 0);
        }
    }
    int crow = (lane >> 4) * 4, ccol = lane & 15;
#pragma unroll
    for (int mr = 0; mr < 4; ++mr)
#pragma unroll
        for (int nc = 0; nc < 2; ++nc)
#pragma unroll
            for (int r = 0; r < 4; ++r) {
                int row = mr * 16 + crow + r;              // 0..63 within tile
                int col = w * 32 + nc * 16 + ccol;         // 0..127
                hs[row * 128 + ((((col >> 3) ^ (row & 7)) << 3) | (col & 7))]
                    = f2bf(fmaxf(acc[mr][nc][r], 0.f));
            }
    __syncthreads();
    // ---- second GEMM: A rows from swizzled LDS
#pragma unroll
    for (int mr = 0; mr < 4; ++mr) { acc[mr][0] = z; acc[mr][1] = z; }
#pragma unroll
    for (int kk = 0; kk < 4; ++kk) {
        bf16x8 b0 = G2p[(kk * 8 + w * 2 + 0) * 64 + lane];
        bf16x8 b1 = G2p[(kk * 8 + w * 2 + 1) * 64 + lane];
#pragma unroll
        for (int mr = 0; mr < 4; ++mr) {
            int row = mr * 16 + ar;
            int cb = kk * 32 + ak;                          // multiple of 8
            bf16x8 a = *(const bf16x8*)(&hs[row * 128 + ((((cb >> 3) ^ (row & 7)) << 3))]);
            acc[mr][0] = __builtin_amdgcn_mfma_f32_16x16x32_bf16(a, b0, acc[mr][0], 0, 0, 0);
            acc[mr][1] = __builtin_amdgcn_mfma_f32_16x16x32_bf16(a, b1, acc[mr][1], 0, 0, 0);
        }
    }
#pragma unroll
    for (int mr = 0; mr < 4; ++mr)
#pragma unroll
        for (int nc = 0; nc < 2; ++nc)
#pragma unroll
            for (int r = 0; r < 4; ++r) {
                int row = node0 + mr * 16 + crow + r;      // write ALL NNP rows
                int col = w * 32 + nc * 16 + ccol;         // wave-uniform branch
                if (col < 64) P2h[(size_t)row * 64 + col] = f2bf(acc[mr][nc][r]);
                else          Q2[(size_t)row * 64 + (col - 64)] = f2bf(acc[mr][nc][r]);
            }
}

// ---------------------- final: padded-batch gather Q2, combine, log_softmax
__global__ __launch_bounds__(256) void final_kernel(const ushort* __restrict__ P2h,
                                                    const ushort* __restrict__ Q2,
                                                    const int* __restrict__ cur,
                                                    const int* __restrict__ slot,
                                                    const float* __restrict__ seaf,
                                                    const float* __restrict__ W2,
                                                    const float* __restrict__ b2,
                                                    float* __restrict__ out) {
    __shared__ int sIdx[4][64];
    int w = threadIdx.x >> 6;
    int node = blockIdx.x * 4 + w;
    int lane = threadIdx.x & 63;
    int half = lane >> 5, cc = lane & 31;
    int cnt = cur[node]; cnt = cnt < CAP ? cnt : CAP;
    sIdx[w][lane] = (lane < cnt) ? slot[node * CAP + lane] : NN;  // NN = zero row
    const uint* q32 = (const uint*)Q2;
    float ax = 0.f, ay = 0.f;
    if (half == 0) {                          // self row (half 0)
        uint u = q32[(size_t)node * 32 + cc];
        ax = bf2f(u & 0xffff); ay = bf2f(u >> 16);
    }
    for (int jp = 0; jp < cnt; jp += 16) {    // full 16-row batches, 8 loads/lane
        int r0 = sIdx[w][jp + 0 + half],  r1 = sIdx[w][jp + 2 + half];
        int r2 = sIdx[w][jp + 4 + half],  r3 = sIdx[w][jp + 6 + half];
        int r4 = sIdx[w][jp + 8 + half],  r5 = sIdx[w][jp + 10 + half];
        int r6 = sIdx[w][jp + 12 + half], r7 = sIdx[w][jp + 14 + half];
        uint u0 = q32[(size_t)r0 * 32 + cc], u1 = q32[(size_t)r1 * 32 + cc];
        uint u2 = q32[(size_t)r2 * 32 + cc], u3 = q32[(size_t)r3 * 32 + cc];
        uint u4 = q32[(size_t)r4 * 32 + cc], u5 = q32[(size_t)r5 * 32 + cc];
        uint u6 = q32[(size_t)r6 * 32 + cc], u7 = q32[(size_t)r7 * 32 + cc];
        ax += ((bf2f(u0 & 0xffff) + bf2f(u1 & 0xffff))
             + (bf2f(u2 & 0xffff) + bf2f(u3 & 0xffff)))
            + ((bf2f(u4 & 0xffff) + bf2f(u5 & 0xffff))
             + (bf2f(u6 & 0xffff) + bf2f(u7 & 0xffff)));
        ay += ((bf2f(u0 >> 16) + bf2f(u1 >> 16))
             + (bf2f(u2 >> 16) + bf2f(u3 >> 16)))
            + ((bf2f(u4 >> 16) + bf2f(u5 >> 16))
             + (bf2f(u6 >> 16) + bf2f(u7 >> 16)));
    }
    ax += __shfl_xor(ax, 32);                 // both halves now hold totals
    ay += __shfl_xor(ay, 32);
    uint up = ((const uint*)P2h)[(size_t)node * 32 + cc];
    float2 w2 = ((const float2*)(W2 + 256 * 64))[cc];
    float2 bv = ((const float2*)b2)[cc];
    float degp = (float)(cnt + 1);
    float sv = seaf[node];
    float v0 = fmaxf(degp * bf2f(up & 0xffff) + ax + sv * w2.x + degp * bv.x, 0.f);
    float v1 = fmaxf(degp * bf2f(up >> 16) + ay + sv * w2.y + degp * bv.y, 0.f);
    float m = (half == 0) ? fmaxf(v0, v1) : -3.4e38f;
#pragma unroll
    for (int o = 1; o < 64; o <<= 1) m = fmaxf(m, __shfl_xor(m, o));
    float s2 = (half == 0) ? (__expf(v0 - m) + __expf(v1 - m)) : 0.f;
#pragma unroll
    for (int o = 1; o < 64; o <<= 1) s2 += __shfl_xor(s2, o);
    float lse = m + __logf(s2);
    if (half == 0)
        ((float2*)out)[(size_t)node * 32 + cc] = make_float2(v0 - lse, v1 - lse);
}

// ---------------------------------------------------------------- launcher
extern "C" void kernel_launch(void* const* d_in, const int* in_sizes, int n_in,
                              void* d_out, int out_size, void* d_ws, size_t ws_size,
                              hipStream_t stream) {
    const float* x  = (const float*)d_in[0];
    const int*   ei = (const int*)d_in[1];
    const float* ea = (const float*)d_in[2];
    const float* W1 = (const float*)d_in[3];
    const float* b1 = (const float*)d_in[4];
    const float* W2 = (const float*)d_in[5];
    const float* b2 = (const float*)d_in[6];
    float* out = (float*)d_out;

    char* ws = (char*)d_ws;
    size_t off_b = 0;
    auto take = [&](size_t bytes) -> void* {
        void* p = ws + off_b;
        off_b += (bytes + 255) & ~(size_t)255;
        return p;
    };
    int*    gh     = (int*)take((size_t)GCH * NBINS * 4);    // fully written by prep
    int*    gbase  = (int*)take((size_t)GCH * NBINS * 4);    // fully written by scan
    int*    tot    = (int*)take((size_t)NBINS * 4);          // fully written by scan
    int2*   coarse = (int2*)take((size_t)NBINS * BINCAP * 8);
    int*    cur    = (int*)take((size_t)NN * 4);             // fully written by binB
    float*  seaf   = (float*)take((size_t)NN * 4);           // fully written by binB
    int*    slot   = (int*)take((size_t)NNP * CAP * 4);
    ushort* xh     = (ushort*)take((size_t)NNP * 64 * 2);    // rows NN.. zeroed by prep
    ushort* F1b    = (ushort*)take((size_t)NNP * 160 * 2);
    ushort* P2h    = (ushort*)take((size_t)NNP * 64 * 2);
    ushort* Q2     = (ushort*)take((size_t)NNP * 64 * 2);
    ushort* G1p    = (ushort*)take(20480 * 2);
    ushort* G2p    = (ushort*)take(16384 * 2);
    (void)in_sizes; (void)n_in; (void)out_size; (void)ws_size;

    prep_kernel<<<3270 + GCH, 256, 0, stream>>>(x, xh, W1, b1, W2, G1p, G2p, ei, gh);
    scan_kernel<<<NBINS, 64, 0, stream>>>(gh, gbase, tot);
    scatter_kernel<<<GCH, 256, 0, stream>>>(ei, ea, gbase, coarse);
    binB_kernel<<<NBLK_B, 256, 0, stream>>>(tot, coarse, cur, seaf, slot);
    agg1_kernel<<<NNP / 4, 256, 0, stream>>>(x, xh, cur, slot, seaf, F1b);
    gemmF_kernel<<<NNP / 64, 256, 0, stream>>>(F1b, (const bf16x8*)G1p,
                                               (const bf16x8*)G2p, P2h, Q2);
    final_kernel<<<NN / 4, 256, 0, stream>>>(P2h, Q2, cur, slot, seaf, W2, b2, out);
}

// Round 13
// 96.843 us; speedup vs baseline: 1.5814x; 1.0596x over previous
//
#include <hip/hip_runtime.h>

#define NN 50000
#define NNP 50048          // NN padded to multiple of 64
#define NE 800000
#define CAP 64             // per-node neighbor capacity (P(deg>64) ~ 2e-18 at lambda=16)

#define NBINS 1024         // coarse bins by dst>>6 (64 nodes/bin)
#define BINSHIFT 6
#define BINCAP 1280        // max records/bin: lambda ~781, +17 sigma
#define GCH 256            // hist/scatter chunks
#define ECHUNK 3125        // NE / GCH
#define NBLK_M 782         // ceil(NNP / 64)

typedef float f32x4 __attribute__((ext_vector_type(4)));
typedef short bf16x8 __attribute__((ext_vector_type(8)));

__device__ __forceinline__ float bf2f(unsigned int u) {
    union { float f; unsigned int i; } v; v.i = u << 16; return v.f;
}
__device__ __forceinline__ unsigned short f2bf(float f) {
    unsigned int i = __float_as_uint(f);
    unsigned int r = i + 0x7FFFu + ((i >> 16) & 1u);
    return (unsigned short)(r >> 16);
}

// --------- prep: xh=bf16(x) (+zero pad rows) | pack G1p/G2p | chunk histograms
__global__ __launch_bounds__(256) void prep_kernel(const float* __restrict__ x,
                                                   ushort* __restrict__ xh,
                                                   const float* __restrict__ W1,
                                                   const float* __restrict__ b1,
                                                   const float* __restrict__ W2,
                                                   ushort* __restrict__ G1p,
                                                   ushort* __restrict__ G2p,
                                                   const int* __restrict__ ei,
                                                   int* __restrict__ gh) {
    __shared__ int hist[NBINS];
    if (blockIdx.x < 3125) {              // 800000 float4 groups of x
        int i = blockIdx.x * 256 + threadIdx.x;
        float4 v = ((const float4*)x)[i];
        ushort4 o;
        o.x = f2bf(v.x); o.y = f2bf(v.y); o.z = f2bf(v.z); o.w = f2bf(v.w);
        ((ushort4*)xh)[i] = o;
        return;
    }
    if (blockIdx.x < 3270) {              // 145 weight-pack blocks
        int wb = blockIdx.x - 3125;
        if (wb == 144) {                  // idle tail block: zero xh pad rows NN..NNP-1
            uint* z = (uint*)(xh + (size_t)NN * 64);
            for (int i = threadIdx.x; i < (NNP - NN) * 32; i += 256) z[i] = 0;
            return;
        }
        int id = wb * 256 + threadIdx.x;
        if (id < 20480) {                 // G1: 160x128 (W1 129 rows + b1 + pad)
            int j = id & 7, l = (id >> 3) & 63, t = id >> 9;
            int kk = t >> 3, n16 = t & 7;
            int k = kk * 32 + ((l >> 4) * 8) + j, n = n16 * 16 + (l & 15);
            float v = (k < 129) ? W1[k * 128 + n] : ((k == 129) ? b1[n] : 0.f);
            G1p[id] = f2bf(v);
        } else if (id < 20480 + 16384) {  // G2: 128x128 = [W2i | W2j]
            int id2 = id - 20480;
            int j = id2 & 7, l = (id2 >> 3) & 63, t = id2 >> 9;
            int kk = t >> 3, n16 = t & 7;
            int k = kk * 32 + ((l >> 4) * 8) + j, n = n16 * 16 + (l & 15);
            float v = (n < 64) ? W2[k * 64 + n] : W2[(128 + k) * 64 + (n - 64)];
            G2p[id2] = f2bf(v);
        }
        return;
    }
    // ---- histogram chunk g
    int g = blockIdx.x - 3270, tid = threadIdx.x;
    for (int b = tid; b < NBINS; b += 256) hist[b] = 0;
    __syncthreads();
    int e0 = g * ECHUNK;
    for (int i = tid; i < ECHUNK; i += 256)
        atomicAdd(&hist[ei[NE + e0 + i] >> BINSHIFT], 1);
    __syncthreads();
    for (int b = tid; b < NBINS; b += 256) gh[g * NBINS + b] = hist[b];
}

// --------- scan: per-bin exclusive prefix over 256 chunk counts (1 wave/bin)
__global__ __launch_bounds__(64) void scan_kernel(const int* __restrict__ gh,
                                                  int* __restrict__ gbase,
                                                  int* __restrict__ tot) {
    int b = blockIdx.x, l = threadIdx.x;
    int v0 = gh[(l * 4 + 0) * NBINS + b];
    int v1 = gh[(l * 4 + 1) * NBINS + b];
    int v2 = gh[(l * 4 + 2) * NBINS + b];
    int v3 = gh[(l * 4 + 3) * NBINS + b];
    int t = v0 + v1 + v2 + v3;
    int s = t;
#pragma unroll
    for (int o = 1; o < 64; o <<= 1) { int u = __shfl_up(s, o); if (l >= o) s += u; }
    int excl = s - t;
    gbase[(l * 4 + 0) * NBINS + b] = excl;
    gbase[(l * 4 + 1) * NBINS + b] = excl + v0;
    gbase[(l * 4 + 2) * NBINS + b] = excl + v0 + v1;
    gbase[(l * 4 + 3) * NBINS + b] = excl + v0 + v1 + v2;
    if (l == 63) tot[b] = s;
}

// --------- scatter: place records at gbase + within-chunk offset (LDS only)
__global__ __launch_bounds__(256) void scatter_kernel(const int* __restrict__ ei,
                                                      const float* __restrict__ ea,
                                                      const int* __restrict__ gbase,
                                                      int2* __restrict__ coarse) {
    __shared__ int curl[NBINS];
    __shared__ int gb[NBINS];
    int g = blockIdx.x, tid = threadIdx.x;
    for (int b = tid; b < NBINS; b += 256) { curl[b] = 0; gb[b] = gbase[g * NBINS + b]; }
    __syncthreads();
    int e0 = g * ECHUNK;
    for (int i = tid; i < ECHUNK; i += 256) {
        int e = e0 + i;
        int s = ei[e];
        int d = ei[NE + e];
        float a = ea[e];
        int b = d >> BINSHIFT;
        int p = atomicAdd(&curl[b], 1) + gb[b];
        if (p < BINCAP)
            coarse[(size_t)b * BINCAP + p] = make_int2(s | ((d & 63) << 16),
                                                       __float_as_int(a));
    }
}

// --------- mid: fused binB + gather + both GEMMs, one block per 64-node bin.
// LDS: slotL (16KB, unioned with hs) + F1 tile [64][168] bf16 (21KB, 336B row
// stride -> 2-way-free ds_read_b128) + curl/seal. ~38KB -> 4 blocks/CU.
__global__ __launch_bounds__(256) void mid_kernel(const int* __restrict__ tot,
                                                  const int2* __restrict__ coarse,
                                                  const float* __restrict__ x,
                                                  const ushort* __restrict__ xh,
                                                  const bf16x8* __restrict__ G1p,
                                                  const bf16x8* __restrict__ G2p,
                                                  int* __restrict__ cur,
                                                  float* __restrict__ seaf,
                                                  int* __restrict__ slot,
                                                  ushort* __restrict__ P2h,
                                                  ushort* __restrict__ Q2) {
    __shared__ union ShU { int slotL[64][64]; ushort hs[64 * 128]; } u;
    __shared__ ushort F1t[64][168];
    __shared__ int curl[64];
    __shared__ float seal[64];
    int b = blockIdx.x, tid = threadIdx.x;
    // phase 0: init
    if (tid < 64) { curl[tid] = 0; seal[tid] = 0.f; }
    for (int i = tid; i < 64 * 64; i += 256) ((int*)u.slotL)[i] = NN;  // pad = zero row
    __syncthreads();
    // phase 1: place this bin's records (LDS atomics); mirror slot to global for final
    int n = tot[b]; n = n < BINCAP ? n : BINCAP;
    for (int i = tid; i < n; i += 256) {
        int2 rec = coarse[(size_t)b * BINCAP + i];
        int s = rec.x & 0xFFFF;
        int dl = (rec.x >> 16) & 63;
        int p = atomicAdd(&curl[dl], 1);
        if (p < CAP) { u.slotL[dl][p] = s; slot[((size_t)(b * 64 + dl)) * CAP + p] = s; }
        atomicAdd(&seal[dl], __int_as_float(rec.y));
    }
    __syncthreads();
    if (tid < 64) {
        int node = b * 64 + tid;
        if (node < NN) { cur[node] = curl[tid]; seaf[node] = seal[tid]; }
    }
    // phase 2: gather xh -> F1 tile in LDS (each wave owns 16 nodes)
    int w = tid >> 6, lane = tid & 63;
    int half = lane >> 5, cc = lane & 31;
    const uint* xh32 = (const uint*)xh;
    for (int i = 0; i < 16; ++i) {
        int nl = w * 16 + i;
        int node = b * 64 + nl;
        uint* rowu = (uint*)&F1t[nl][0];          // 336B row base, 16B aligned
        if (node >= NN) {                         // zero pad rows
            rowu[half * 32 + cc] = 0;             // cols 0..127
            if (lane < 16) rowu[64 + lane] = 0;   // cols 128..159
            continue;
        }
        int cnt = curl[nl]; cnt = cnt < CAP ? cnt : CAP;
        float ax = 0.f, ay = 0.f;
        for (int jp = 0; jp < cnt; jp += 16) {    // full 16-row batches, 8 loads/lane
            int r0 = u.slotL[nl][jp + 0 + half],  r1 = u.slotL[nl][jp + 2 + half];
            int r2 = u.slotL[nl][jp + 4 + half],  r3 = u.slotL[nl][jp + 6 + half];
            int r4 = u.slotL[nl][jp + 8 + half],  r5 = u.slotL[nl][jp + 10 + half];
            int r6 = u.slotL[nl][jp + 12 + half], r7 = u.slotL[nl][jp + 14 + half];
            uint u0 = xh32[r0 * 32 + cc], u1 = xh32[r1 * 32 + cc];
            uint u2 = xh32[r2 * 32 + cc], u3 = xh32[r3 * 32 + cc];
            uint u4 = xh32[r4 * 32 + cc], u5 = xh32[r5 * 32 + cc];
            uint u6 = xh32[r6 * 32 + cc], u7 = xh32[r7 * 32 + cc];
            ax += ((bf2f(u0 & 0xffff) + bf2f(u1 & 0xffff))
                 + (bf2f(u2 & 0xffff) + bf2f(u3 & 0xffff)))
                + ((bf2f(u4 & 0xffff) + bf2f(u5 & 0xffff))
                 + (bf2f(u6 & 0xffff) + bf2f(u7 & 0xffff)));
            ay += ((bf2f(u0 >> 16) + bf2f(u1 >> 16))
                 + (bf2f(u2 >> 16) + bf2f(u3 >> 16)))
                + ((bf2f(u4 >> 16) + bf2f(u5 >> 16))
                 + (bf2f(u6 >> 16) + bf2f(u7 >> 16)));
        }
        ax += __shfl_xor(ax, 32);                 // merge halves
        ay += __shfl_xor(ay, 32);
        float2 xv = ((const float2*)x)[node * 32 + cc];
        float degp = (float)(cnt + 1);
        if (half == 0)                            // sum segment [64:128): + self
            rowu[32 + cc] = (uint)f2bf(ax + xv.x) | ((uint)f2bf(ay + xv.y) << 16);
        else                                      // scaled-self segment [0:64)
            rowu[cc] = (uint)f2bf(degp * xv.x) | ((uint)f2bf(degp * xv.y) << 16);
        if (lane < 32) {
            ushort z = 0;
            if (lane == 0) z = f2bf(seal[nl]);
            else if (lane == 1) z = f2bf(degp);
            F1t[nl][128 + lane] = z;
        }
    }
    __syncthreads();                              // F1 done; slotL dead
    // phase 3: GEMM1 h = relu(F1t @ G1) -> swizzled hs (overwrites slotL)
    int node0 = b * 64;
    int ar = lane & 15, ak = (lane >> 4) * 8;
    f32x4 z4 = {0.f, 0.f, 0.f, 0.f};
    f32x4 acc[4][2];
#pragma unroll
    for (int mr = 0; mr < 4; ++mr) { acc[mr][0] = z4; acc[mr][1] = z4; }
#pragma unroll
    for (int kk = 0; kk < 5; ++kk) {
        bf16x8 b0 = G1p[(kk * 8 + w * 2 + 0) * 64 + lane];
        bf16x8 b1 = G1p[(kk * 8 + w * 2 + 1) * 64 + lane];
#pragma unroll
        for (int mr = 0; mr < 4; ++mr) {
            bf16x8 a = *(const bf16x8*)(&F1t[mr * 16 + ar][kk * 32 + ak]);
            acc[mr][0] = __builtin_amdgcn_mfma_f32_16x16x32_bf16(a, b0, acc[mr][0], 0, 0, 0);
            acc[mr][1] = __builtin_amdgcn_mfma_f32_16x16x32_bf16(a, b1, acc[mr][1], 0, 0, 0);
        }
    }
    int crow = (lane >> 4) * 4, ccol = lane & 15;
#pragma unroll
    for (int mr = 0; mr < 4; ++mr)
#pragma unroll
        for (int nc = 0; nc < 2; ++nc)
#pragma unroll
            for (int r = 0; r < 4; ++r) {
                int row = mr * 16 + crow + r;
                int col = w * 32 + nc * 16 + ccol;
                u.hs[row * 128 + ((((col >> 3) ^ (row & 7)) << 3) | (col & 7))]
                    = f2bf(fmaxf(acc[mr][nc][r], 0.f));
            }
    __syncthreads();
    // phase 4: GEMM2 [P2|Q2] = h @ G2 from swizzled hs
#pragma unroll
    for (int mr = 0; mr < 4; ++mr) { acc[mr][0] = z4; acc[mr][1] = z4; }
#pragma unroll
    for (int kk = 0; kk < 4; ++kk) {
        bf16x8 b0 = G2p[(kk * 8 + w * 2 + 0) * 64 + lane];
        bf16x8 b1 = G2p[(kk * 8 + w * 2 + 1) * 64 + lane];
#pragma unroll
        for (int mr = 0; mr < 4; ++mr) {
            int row = mr * 16 + ar;
            int cb = kk * 32 + ak;
            bf16x8 a = *(const bf16x8*)(&u.hs[row * 128 + ((((cb >> 3) ^ (row & 7)) << 3))]);
            acc[mr][0] = __builtin_amdgcn_mfma_f32_16x16x32_bf16(a, b0, acc[mr][0], 0, 0, 0);
            acc[mr][1] = __builtin_amdgcn_mfma_f32_16x16x32_bf16(a, b1, acc[mr][1], 0, 0, 0);
        }
    }
#pragma unroll
    for (int mr = 0; mr < 4; ++mr)
#pragma unroll
        for (int nc = 0; nc < 2; ++nc)
#pragma unroll
            for (int r = 0; r < 4; ++r) {
                int row = node0 + mr * 16 + crow + r;      // write ALL NNP rows
                int col = w * 32 + nc * 16 + ccol;         // wave-uniform branch
                if (col < 64) P2h[(size_t)row * 64 + col] = f2bf(acc[mr][nc][r]);
                else          Q2[(size_t)row * 64 + (col - 64)] = f2bf(acc[mr][nc][r]);
            }
}

// ---------------------- final: padded-batch gather Q2, combine, log_softmax
__global__ __launch_bounds__(256) void final_kernel(const ushort* __restrict__ P2h,
                                                    const ushort* __restrict__ Q2,
                                                    const int* __restrict__ cur,
                                                    const int* __restrict__ slot,
                                                    const float* __restrict__ seaf,
                                                    const float* __restrict__ W2,
                                                    const float* __restrict__ b2,
                                                    float* __restrict__ out) {
    __shared__ int sIdx[4][64];
    int w = threadIdx.x >> 6;
    int node = blockIdx.x * 4 + w;
    int lane = threadIdx.x & 63;
    int half = lane >> 5, cc = lane & 31;
    int cnt = cur[node]; cnt = cnt < CAP ? cnt : CAP;
    sIdx[w][lane] = (lane < cnt) ? slot[node * CAP + lane] : NN;  // NN = zero row
    const uint* q32 = (const uint*)Q2;
    float ax = 0.f, ay = 0.f;
    if (half == 0) {                          // self row (half 0)
        uint u = q32[(size_t)node * 32 + cc];
        ax = bf2f(u & 0xffff); ay = bf2f(u >> 16);
    }
    for (int jp = 0; jp < cnt; jp += 16) {    // full 16-row batches, 8 loads/lane
        int r0 = sIdx[w][jp + 0 + half],  r1 = sIdx[w][jp + 2 + half];
        int r2 = sIdx[w][jp + 4 + half],  r3 = sIdx[w][jp + 6 + half];
        int r4 = sIdx[w][jp + 8 + half],  r5 = sIdx[w][jp + 10 + half];
        int r6 = sIdx[w][jp + 12 + half], r7 = sIdx[w][jp + 14 + half];
        uint u0 = q32[(size_t)r0 * 32 + cc], u1 = q32[(size_t)r1 * 32 + cc];
        uint u2 = q32[(size_t)r2 * 32 + cc], u3 = q32[(size_t)r3 * 32 + cc];
        uint u4 = q32[(size_t)r4 * 32 + cc], u5 = q32[(size_t)r5 * 32 + cc];
        uint u6 = q32[(size_t)r6 * 32 + cc], u7 = q32[(size_t)r7 * 32 + cc];
        ax += ((bf2f(u0 & 0xffff) + bf2f(u1 & 0xffff))
             + (bf2f(u2 & 0xffff) + bf2f(u3 & 0xffff)))
            + ((bf2f(u4 & 0xffff) + bf2f(u5 & 0xffff))
             + (bf2f(u6 & 0xffff) + bf2f(u7 & 0xffff)));
        ay += ((bf2f(u0 >> 16) + bf2f(u1 >> 16))
             + (bf2f(u2 >> 16) + bf2f(u3 >> 16)))
            + ((bf2f(u4 >> 16) + bf2f(u5 >> 16))
             + (bf2f(u6 >> 16) + bf2f(u7 >> 16)));
    }
    ax += __shfl_xor(ax, 32);                 // both halves now hold totals
    ay += __shfl_xor(ay, 32);
    uint up = ((const uint*)P2h)[(size_t)node * 32 + cc];
    float2 w2 = ((const float2*)(W2 + 256 * 64))[cc];
    float2 bv = ((const float2*)b2)[cc];
    float degp = (float)(cnt + 1);
    float sv = seaf[node];
    float v0 = fmaxf(degp * bf2f(up & 0xffff) + ax + sv * w2.x + degp * bv.x, 0.f);
    float v1 = fmaxf(degp * bf2f(up >> 16) + ay + sv * w2.y + degp * bv.y, 0.f);
    float m = (half == 0) ? fmaxf(v0, v1) : -3.4e38f;
#pragma unroll
    for (int o = 1; o < 64; o <<= 1) m = fmaxf(m, __shfl_xor(m, o));
    float s2 = (half == 0) ? (__expf(v0 - m) + __expf(v1 - m)) : 0.f;
#pragma unroll
    for (int o = 1; o < 64; o <<= 1) s2 += __shfl_xor(s2, o);
    float lse = m + __logf(s2);
    if (half == 0)
        ((float2*)out)[(size_t)node * 32 + cc] = make_float2(v0 - lse, v1 - lse);
}

// ---------------------------------------------------------------- launcher
extern "C" void kernel_launch(void* const* d_in, const int* in_sizes, int n_in,
                              void* d_out, int out_size, void* d_ws, size_t ws_size,
                              hipStream_t stream) {
    const float* x  = (const float*)d_in[0];
    const int*   ei = (const int*)d_in[1];
    const float* ea = (const float*)d_in[2];
    const float* W1 = (const float*)d_in[3];
    const float* b1 = (const float*)d_in[4];
    const float* W2 = (const float*)d_in[5];
    const float* b2 = (const float*)d_in[6];
    float* out = (float*)d_out;

    char* ws = (char*)d_ws;
    size_t off_b = 0;
    auto take = [&](size_t bytes) -> void* {
        void* p = ws + off_b;
        off_b += (bytes + 255) & ~(size_t)255;
        return p;
    };
    int*    gh     = (int*)take((size_t)GCH * NBINS * 4);    // fully written by prep
    int*    gbase  = (int*)take((size_t)GCH * NBINS * 4);    // fully written by scan
    int*    tot    = (int*)take((size_t)NBINS * 4);          // fully written by scan
    int2*   coarse = (int2*)take((size_t)NBINS * BINCAP * 8);
    int*    cur    = (int*)take((size_t)NN * 4);             // fully written by mid
    float*  seaf   = (float*)take((size_t)NN * 4);           // fully written by mid
    int*    slot   = (int*)take((size_t)NNP * CAP * 4);
    ushort* xh     = (ushort*)take((size_t)NNP * 64 * 2);    // rows NN.. zeroed by prep
    ushort* P2h    = (ushort*)take((size_t)NNP * 64 * 2);
    ushort* Q2     = (ushort*)take((size_t)NNP * 64 * 2);
    ushort* G1p    = (ushort*)take(20480 * 2);
    ushort* G2p    = (ushort*)take(16384 * 2);
    (void)in_sizes; (void)n_in; (void)out_size; (void)ws_size;

    prep_kernel<<<3270 + GCH, 256, 0, stream>>>(x, xh, W1, b1, W2, G1p, G2p, ei, gh);
    scan_kernel<<<NBINS, 64, 0, stream>>>(gh, gbase, tot);
    scatter_kernel<<<GCH, 256, 0, stream>>>(ei, ea, gbase, coarse);
    mid_kernel<<<NBLK_M, 256, 0, stream>>>(tot, coarse, x, xh,
                                           (const bf16x8*)G1p, (const bf16x8*)G2p,
                                           cur, seaf, slot, P2h, Q2);
    final_kernel<<<NN / 4, 256, 0, stream>>>(P2h, Q2, cur, slot, seaf, W2, b2, out);
}

// Round 14
// 83.343 us; speedup vs baseline: 1.8376x; 1.1620x over previous
//
#include <hip/hip_runtime.h>

#define NN 50000
#define NNP 50048          // NN padded to multiple of 64
#define NE 800000
#define CAP 64             // per-node neighbor capacity (P(deg>64) ~ 2e-18 at lambda=16)

#define NBINS 1024         // coarse bins by dst>>6 (64 nodes/bin)
#define BINSHIFT 6
#define BINCAP 1280        // max records/bin: lambda ~781, +17 sigma
#define GCH 256            // hist/scatter chunks
#define ECHUNK 3125        // NE / GCH
#define NBLK_M 782         // ceil(NNP / 64)

typedef float f32x4 __attribute__((ext_vector_type(4)));
typedef short bf16x8 __attribute__((ext_vector_type(8)));

__device__ __forceinline__ float bf2f(unsigned int u) {
    union { float f; unsigned int i; } v; v.i = u << 16; return v.f;
}
__device__ __forceinline__ unsigned short f2bf(float f) {
    unsigned int i = __float_as_uint(f);
    unsigned int r = i + 0x7FFFu + ((i >> 16) & 1u);
    return (unsigned short)(r >> 16);
}
__device__ __forceinline__ uint pk2(float lo, float hi) {
    return (uint)f2bf(lo) | ((uint)f2bf(hi) << 16);
}

// --------- prep: xh=bf16(x) (+zero pad rows) | pack G1p/G2p | chunk histograms
__global__ __launch_bounds__(256) void prep_kernel(const float* __restrict__ x,
                                                   ushort* __restrict__ xh,
                                                   const float* __restrict__ W1,
                                                   const float* __restrict__ b1,
                                                   const float* __restrict__ W2,
                                                   ushort* __restrict__ G1p,
                                                   ushort* __restrict__ G2p,
                                                   const int* __restrict__ ei,
                                                   int* __restrict__ gh) {
    __shared__ int hist[NBINS];
    if (blockIdx.x < 3125) {              // 800000 float4 groups of x
        int i = blockIdx.x * 256 + threadIdx.x;
        float4 v = ((const float4*)x)[i];
        ushort4 o;
        o.x = f2bf(v.x); o.y = f2bf(v.y); o.z = f2bf(v.z); o.w = f2bf(v.w);
        ((ushort4*)xh)[i] = o;
        return;
    }
    if (blockIdx.x < 3270) {              // 145 weight-pack blocks
        int wb = blockIdx.x - 3125;
        if (wb == 144) {                  // idle tail block: zero xh pad rows NN..NNP-1
            uint* z = (uint*)(xh + (size_t)NN * 64);
            for (int i = threadIdx.x; i < (NNP - NN) * 32; i += 256) z[i] = 0;
            return;
        }
        int id = wb * 256 + threadIdx.x;
        if (id < 20480) {                 // G1: 160x128 (W1 129 rows + b1 + pad)
            int j = id & 7, l = (id >> 3) & 63, t = id >> 9;
            int kk = t >> 3, n16 = t & 7;
            int k = kk * 32 + ((l >> 4) * 8) + j, n = n16 * 16 + (l & 15);
            float v = (k < 129) ? W1[k * 128 + n] : ((k == 129) ? b1[n] : 0.f);
            G1p[id] = f2bf(v);
        } else if (id < 20480 + 16384) {  // G2: 128x128 = [W2i | W2j]
            int id2 = id - 20480;
            int j = id2 & 7, l = (id2 >> 3) & 63, t = id2 >> 9;
            int kk = t >> 3, n16 = t & 7;
            int k = kk * 32 + ((l >> 4) * 8) + j, n = n16 * 16 + (l & 15);
            float v = (n < 64) ? W2[k * 64 + n] : W2[(128 + k) * 64 + (n - 64)];
            G2p[id2] = f2bf(v);
        }
        return;
    }
    // ---- histogram chunk g
    int g = blockIdx.x - 3270, tid = threadIdx.x;
    for (int b = tid; b < NBINS; b += 256) hist[b] = 0;
    __syncthreads();
    int e0 = g * ECHUNK;
    for (int i = tid; i < ECHUNK; i += 256)
        atomicAdd(&hist[ei[NE + e0 + i] >> BINSHIFT], 1);
    __syncthreads();
    for (int b = tid; b < NBINS; b += 256) gh[g * NBINS + b] = hist[b];
}

// --------- scan: per-bin exclusive prefix over 256 chunk counts (1 wave/bin)
__global__ __launch_bounds__(64) void scan_kernel(const int* __restrict__ gh,
                                                  int* __restrict__ gbase,
                                                  int* __restrict__ tot) {
    int b = blockIdx.x, l = threadIdx.x;
    int v0 = gh[(l * 4 + 0) * NBINS + b];
    int v1 = gh[(l * 4 + 1) * NBINS + b];
    int v2 = gh[(l * 4 + 2) * NBINS + b];
    int v3 = gh[(l * 4 + 3) * NBINS + b];
    int t = v0 + v1 + v2 + v3;
    int s = t;
#pragma unroll
    for (int o = 1; o < 64; o <<= 1) { int u = __shfl_up(s, o); if (l >= o) s += u; }
    int excl = s - t;
    gbase[(l * 4 + 0) * NBINS + b] = excl;
    gbase[(l * 4 + 1) * NBINS + b] = excl + v0;
    gbase[(l * 4 + 2) * NBINS + b] = excl + v0 + v1;
    gbase[(l * 4 + 3) * NBINS + b] = excl + v0 + v1 + v2;
    if (l == 63) tot[b] = s;
}

// --------- scatter: place records at gbase + within-chunk offset (LDS only)
__global__ __launch_bounds__(256) void scatter_kernel(const int* __restrict__ ei,
                                                      const float* __restrict__ ea,
                                                      const int* __restrict__ gbase,
                                                      int2* __restrict__ coarse) {
    __shared__ int curl[NBINS];
    __shared__ int gb[NBINS];
    int g = blockIdx.x, tid = threadIdx.x;
    for (int b = tid; b < NBINS; b += 256) { curl[b] = 0; gb[b] = gbase[g * NBINS + b]; }
    __syncthreads();
    int e0 = g * ECHUNK;
    for (int i = tid; i < ECHUNK; i += 256) {
        int e = e0 + i;
        int s = ei[e];
        int d = ei[NE + e];
        float a = ea[e];
        int b = d >> BINSHIFT;
        int p = atomicAdd(&curl[b], 1) + gb[b];
        if (p < BINCAP)
            coarse[(size_t)b * BINCAP + p] = make_int2(s | ((d & 63) << 16),
                                                       __float_as_int(a));
    }
}

// --------- mid: fused placement + quarter-per-node gather + both GEMMs.
__global__ __launch_bounds__(256) void mid_kernel(const int* __restrict__ tot,
                                                  const int2* __restrict__ coarse,
                                                  const float* __restrict__ x,
                                                  const ushort* __restrict__ xh,
                                                  const bf16x8* __restrict__ G1p,
                                                  const bf16x8* __restrict__ G2p,
                                                  int* __restrict__ cur,
                                                  float* __restrict__ seaf,
                                                  int* __restrict__ slot,
                                                  ushort* __restrict__ P2h,
                                                  ushort* __restrict__ Q2) {
    __shared__ union ShU { int slotL[64][65]; ushort hs[64 * 128]; } u;  // 16.6KB
    __shared__ ushort F1t[64][168];       // 21KB, 336B row stride
    __shared__ int curl[64];
    __shared__ float seal[64];
    int b = blockIdx.x, tid = threadIdx.x;
    // phase 0: init
    if (tid < 64) { curl[tid] = 0; seal[tid] = 0.f; }
    for (int i = tid; i < 64 * 65; i += 256) ((int*)u.slotL)[i] = NN;  // pad = zero row
    __syncthreads();
    // phase 1: place this bin's records (LDS atomics); mirror slot to global for final
    int n = tot[b]; n = n < BINCAP ? n : BINCAP;
    for (int i = tid; i < n; i += 256) {
        int2 rec = coarse[(size_t)b * BINCAP + i];
        int s = rec.x & 0xFFFF;
        int dl = (rec.x >> 16) & 63;
        int p = atomicAdd(&curl[dl], 1);
        if (p < CAP) { u.slotL[dl][p] = s; slot[((size_t)(b * 64 + dl)) * CAP + p] = s; }
        atomicAdd(&seal[dl], __int_as_float(rec.y));
    }
    __syncthreads();
    if (tid < 64) {
        int node = b * 64 + tid;
        if (node < NN) { cur[node] = curl[tid]; seaf[node] = seal[tid]; }
    }
    // phase 2: quarter-per-node gather (4 nodes in flight per wave)
    int w = tid >> 6, lane = tid & 63;
    int q = lane >> 4, ql = lane & 15;        // quarter, lane-in-quarter
    const uint2* xh64 = (const uint2*)xh;     // 4 ch per lane, 16 lanes = 128B row
    for (int i = 0; i < 4; ++i) {
        int nl = w * 16 + q * 4 + i;
        int node = b * 64 + nl;
        uint2* row2 = (uint2*)&F1t[nl][0];
        if (node >= NN) {                     // zero pad rows
            row2[ql] = make_uint2(0, 0);
            row2[16 + ql] = make_uint2(0, 0);
            ((uint*)&F1t[nl][128])[ql] = 0;
            continue;
        }
        int cnt = curl[nl]; cnt = cnt < CAP ? cnt : CAP;
        float a0 = 0.f, a1 = 0.f, a2 = 0.f, a3 = 0.f;
        for (int jp = 0; jp < cnt; jp += 8) { // 8 rows in flight per quarter
            int r0 = u.slotL[nl][jp + 0], r1 = u.slotL[nl][jp + 1];
            int r2 = u.slotL[nl][jp + 2], r3 = u.slotL[nl][jp + 3];
            int r4 = u.slotL[nl][jp + 4], r5 = u.slotL[nl][jp + 5];
            int r6 = u.slotL[nl][jp + 6], r7 = u.slotL[nl][jp + 7];
            uint2 u0 = xh64[(size_t)r0 * 16 + ql], u1 = xh64[(size_t)r1 * 16 + ql];
            uint2 u2 = xh64[(size_t)r2 * 16 + ql], u3 = xh64[(size_t)r3 * 16 + ql];
            uint2 u4 = xh64[(size_t)r4 * 16 + ql], u5 = xh64[(size_t)r5 * 16 + ql];
            uint2 u6 = xh64[(size_t)r6 * 16 + ql], u7 = xh64[(size_t)r7 * 16 + ql];
            a0 += ((bf2f(u0.x & 0xffff) + bf2f(u1.x & 0xffff))
                 + (bf2f(u2.x & 0xffff) + bf2f(u3.x & 0xffff)))
                + ((bf2f(u4.x & 0xffff) + bf2f(u5.x & 0xffff))
                 + (bf2f(u6.x & 0xffff) + bf2f(u7.x & 0xffff)));
            a1 += ((bf2f(u0.x >> 16) + bf2f(u1.x >> 16))
                 + (bf2f(u2.x >> 16) + bf2f(u3.x >> 16)))
                + ((bf2f(u4.x >> 16) + bf2f(u5.x >> 16))
                 + (bf2f(u6.x >> 16) + bf2f(u7.x >> 16)));
            a2 += ((bf2f(u0.y & 0xffff) + bf2f(u1.y & 0xffff))
                 + (bf2f(u2.y & 0xffff) + bf2f(u3.y & 0xffff)))
                + ((bf2f(u4.y & 0xffff) + bf2f(u5.y & 0xffff))
                 + (bf2f(u6.y & 0xffff) + bf2f(u7.y & 0xffff)));
            a3 += ((bf2f(u0.y >> 16) + bf2f(u1.y >> 16))
                 + (bf2f(u2.y >> 16) + bf2f(u3.y >> 16)))
                + ((bf2f(u4.y >> 16) + bf2f(u5.y >> 16))
                 + (bf2f(u6.y >> 16) + bf2f(u7.y >> 16)));
        }
        float4 xv = ((const float4*)x)[(size_t)node * 16 + ql];
        float degp = (float)(cnt + 1);
        row2[ql] = make_uint2(pk2(degp * xv.x, degp * xv.y),
                              pk2(degp * xv.z, degp * xv.w));
        row2[16 + ql] = make_uint2(pk2(a0 + xv.x, a1 + xv.y),
                                   pk2(a2 + xv.z, a3 + xv.w));
        uint ex = 0;
        if (ql == 0) ex = pk2(seal[nl], degp);
        ((uint*)&F1t[nl][128])[ql] = ex;
    }
    __syncthreads();                              // F1 done; slotL dead
    // phase 3: GEMM1 h = relu(F1t @ G1) -> swizzled hs (overwrites slotL)
    int node0 = b * 64;
    int ar = lane & 15, ak = (lane >> 4) * 8;
    f32x4 z4 = {0.f, 0.f, 0.f, 0.f};
    f32x4 acc[4][2];
#pragma unroll
    for (int mr = 0; mr < 4; ++mr) { acc[mr][0] = z4; acc[mr][1] = z4; }
#pragma unroll
    for (int kk = 0; kk < 5; ++kk) {
        bf16x8 b0 = G1p[(kk * 8 + w * 2 + 0) * 64 + lane];
        bf16x8 b1 = G1p[(kk * 8 + w * 2 + 1) * 64 + lane];
#pragma unroll
        for (int mr = 0; mr < 4; ++mr) {
            bf16x8 a = *(const bf16x8*)(&F1t[mr * 16 + ar][kk * 32 + ak]);
            acc[mr][0] = __builtin_amdgcn_mfma_f32_16x16x32_bf16(a, b0, acc[mr][0], 0, 0, 0);
            acc[mr][1] = __builtin_amdgcn_mfma_f32_16x16x32_bf16(a, b1, acc[mr][1], 0, 0, 0);
        }
    }
    int crow = (lane >> 4) * 4, ccol = lane & 15;
#pragma unroll
    for (int mr = 0; mr < 4; ++mr)
#pragma unroll
        for (int nc = 0; nc < 2; ++nc)
#pragma unroll
            for (int r = 0; r < 4; ++r) {
                int row = mr * 16 + crow + r;
                int col = w * 32 + nc * 16 + ccol;
                u.hs[row * 128 + ((((col >> 3) ^ (row & 7)) << 3) | (col & 7))]
                    = f2bf(fmaxf(acc[mr][nc][r], 0.f));
            }
    __syncthreads();
    // phase 4: GEMM2 [P2|Q2] = h @ G2 from swizzled hs
#pragma unroll
    for (int mr = 0; mr < 4; ++mr) { acc[mr][0] = z4; acc[mr][1] = z4; }
#pragma unroll
    for (int kk = 0; kk < 4; ++kk) {
        bf16x8 b0 = G2p[(kk * 8 + w * 2 + 0) * 64 + lane];
        bf16x8 b1 = G2p[(kk * 8 + w * 2 + 1) * 64 + lane];
#pragma unroll
        for (int mr = 0; mr < 4; ++mr) {
            int row = mr * 16 + ar;
            int cb = kk * 32 + ak;
            bf16x8 a = *(const bf16x8*)(&u.hs[row * 128 + ((((cb >> 3) ^ (row & 7)) << 3))]);
            acc[mr][0] = __builtin_amdgcn_mfma_f32_16x16x32_bf16(a, b0, acc[mr][0], 0, 0, 0);
            acc[mr][1] = __builtin_amdgcn_mfma_f32_16x16x32_bf16(a, b1, acc[mr][1], 0, 0, 0);
        }
    }
#pragma unroll
    for (int mr = 0; mr < 4; ++mr)
#pragma unroll
        for (int nc = 0; nc < 2; ++nc)
#pragma unroll
            for (int r = 0; r < 4; ++r) {
                int row = node0 + mr * 16 + crow + r;      // write ALL NNP rows
                int col = w * 32 + nc * 16 + ccol;         // wave-uniform branch
                if (col < 64) P2h[(size_t)row * 64 + col] = f2bf(acc[mr][nc][r]);
                else          Q2[(size_t)row * 64 + (col - 64)] = f2bf(acc[mr][nc][r]);
            }
}

// ------- final: quarter-per-node gather Q2, combine, quarter log_softmax
__global__ __launch_bounds__(256) void final_kernel(const ushort* __restrict__ P2h,
                                                    const ushort* __restrict__ Q2,
                                                    const int* __restrict__ cur,
                                                    const int* __restrict__ slot,
                                                    const float* __restrict__ seaf,
                                                    const float* __restrict__ W2,
                                                    const float* __restrict__ b2,
                                                    float* __restrict__ out) {
    __shared__ int sIdxL[16][65];             // padded stride: quarter bank spread
    int tid = threadIdx.x;
    int w = tid >> 6, lane = tid & 63;
    int q = lane >> 4, ql = lane & 15;
    int nbase = blockIdx.x * 16;              // grid = NN/16 = 3125 exactly
    for (int k = tid; k < 1024; k += 256) {   // stage 16 nodes x 64 idx
        int n_l = k >> 6, j = k & 63;
        int node = nbase + n_l;
        int cnt = cur[node]; cnt = cnt < CAP ? cnt : CAP;
        sIdxL[n_l][j] = (j < cnt) ? slot[(size_t)node * CAP + j] : NN;  // NN = zero row
    }
    __syncthreads();
    int nl = w * 4 + q;
    int node = nbase + nl;
    int cnt = cur[node]; cnt = cnt < CAP ? cnt : CAP;
    const uint2* q64 = (const uint2*)Q2;
    uint2 us = q64[(size_t)node * 16 + ql];   // self row
    float a0 = bf2f(us.x & 0xffff), a1 = bf2f(us.x >> 16);
    float a2 = bf2f(us.y & 0xffff), a3 = bf2f(us.y >> 16);
    for (int jp = 0; jp < cnt; jp += 8) {     // 8 rows in flight per quarter
        int r0 = sIdxL[nl][jp + 0], r1 = sIdxL[nl][jp + 1];
        int r2 = sIdxL[nl][jp + 2], r3 = sIdxL[nl][jp + 3];
        int r4 = sIdxL[nl][jp + 4], r5 = sIdxL[nl][jp + 5];
        int r6 = sIdxL[nl][jp + 6], r7 = sIdxL[nl][jp + 7];
        uint2 u0 = q64[(size_t)r0 * 16 + ql], u1 = q64[(size_t)r1 * 16 + ql];
        uint2 u2 = q64[(size_t)r2 * 16 + ql], u3 = q64[(size_t)r3 * 16 + ql];
        uint2 u4 = q64[(size_t)r4 * 16 + ql], u5 = q64[(size_t)r5 * 16 + ql];
        uint2 u6 = q64[(size_t)r6 * 16 + ql], u7 = q64[(size_t)r7 * 16 + ql];
        a0 += ((bf2f(u0.x & 0xffff) + bf2f(u1.x & 0xffff))
             + (bf2f(u2.x & 0xffff) + bf2f(u3.x & 0xffff)))
            + ((bf2f(u4.x & 0xffff) + bf2f(u5.x & 0xffff))
             + (bf2f(u6.x & 0xffff) + bf2f(u7.x & 0xffff)));
        a1 += ((bf2f(u0.x >> 16) + bf2f(u1.x >> 16))
             + (bf2f(u2.x >> 16) + bf2f(u3.x >> 16)))
            + ((bf2f(u4.x >> 16) + bf2f(u5.x >> 16))
             + (bf2f(u6.x >> 16) + bf2f(u7.x >> 16)));
        a2 += ((bf2f(u0.y & 0xffff) + bf2f(u1.y & 0xffff))
             + (bf2f(u2.y & 0xffff) + bf2f(u3.y & 0xffff)))
            + ((bf2f(u4.y & 0xffff) + bf2f(u5.y & 0xffff))
             + (bf2f(u6.y & 0xffff) + bf2f(u7.y & 0xffff)));
        a3 += ((bf2f(u0.y >> 16) + bf2f(u1.y >> 16))
             + (bf2f(u2.y >> 16) + bf2f(u3.y >> 16)))
            + ((bf2f(u4.y >> 16) + bf2f(u5.y >> 16))
             + (bf2f(u6.y >> 16) + bf2f(u7.y >> 16)));
    }
    uint2 up = ((const uint2*)P2h)[(size_t)node * 16 + ql];
    float4 w2 = ((const float4*)(W2 + 256 * 64))[ql];
    float4 bv = ((const float4*)b2)[ql];
    float degp = (float)(cnt + 1);
    float sv = seaf[node];
    float v0 = fmaxf(degp * bf2f(up.x & 0xffff) + a0 + sv * w2.x + degp * bv.x, 0.f);
    float v1 = fmaxf(degp * bf2f(up.x >> 16) + a1 + sv * w2.y + degp * bv.y, 0.f);
    float v2 = fmaxf(degp * bf2f(up.y & 0xffff) + a2 + sv * w2.z + degp * bv.z, 0.f);
    float v3 = fmaxf(degp * bf2f(up.y >> 16) + a3 + sv * w2.w + degp * bv.w, 0.f);
    float m = fmaxf(fmaxf(v0, v1), fmaxf(v2, v3));
#pragma unroll
    for (int o = 1; o < 16; o <<= 1) m = fmaxf(m, __shfl_xor(m, o));   // quarter max
    float s2 = __expf(v0 - m) + __expf(v1 - m) + __expf(v2 - m) + __expf(v3 - m);
#pragma unroll
    for (int o = 1; o < 16; o <<= 1) s2 += __shfl_xor(s2, o);          // quarter sum
    float lse = m + __logf(s2);
    float4 r;
    r.x = v0 - lse; r.y = v1 - lse; r.z = v2 - lse; r.w = v3 - lse;
    ((float4*)out)[(size_t)node * 16 + ql] = r;
}

// ---------------------------------------------------------------- launcher
extern "C" void kernel_launch(void* const* d_in, const int* in_sizes, int n_in,
                              void* d_out, int out_size, void* d_ws, size_t ws_size,
                              hipStream_t stream) {
    const float* x  = (const float*)d_in[0];
    const int*   ei = (const int*)d_in[1];
    const float* ea = (const float*)d_in[2];
    const float* W1 = (const float*)d_in[3];
    const float* b1 = (const float*)d_in[4];
    const float* W2 = (const float*)d_in[5];
    const float* b2 = (const float*)d_in[6];
    float* out = (float*)d_out;

    char* ws = (char*)d_ws;
    size_t off_b = 0;
    auto take = [&](size_t bytes) -> void* {
        void* p = ws + off_b;
        off_b += (bytes + 255) & ~(size_t)255;
        return p;
    };
    int*    gh     = (int*)take((size_t)GCH * NBINS * 4);    // fully written by prep
    int*    gbase  = (int*)take((size_t)GCH * NBINS * 4);    // fully written by scan
    int*    tot    = (int*)take((size_t)NBINS * 4);          // fully written by scan
    int2*   coarse = (int2*)take((size_t)NBINS * BINCAP * 8);
    int*    cur    = (int*)take((size_t)NN * 4);             // fully written by mid
    float*  seaf   = (float*)take((size_t)NN * 4);           // fully written by mid
    int*    slot   = (int*)take((size_t)NNP * CAP * 4);
    ushort* xh     = (ushort*)take((size_t)NNP * 64 * 2);    // rows NN.. zeroed by prep
    ushort* P2h    = (ushort*)take((size_t)NNP * 64 * 2);
    ushort* Q2     = (ushort*)take((size_t)NNP * 64 * 2);
    ushort* G1p    = (ushort*)take(20480 * 2);
    ushort* G2p    = (ushort*)take(16384 * 2);
    (void)in_sizes; (void)n_in; (void)out_size; (void)ws_size;

    prep_kernel<<<3270 + GCH, 256, 0, stream>>>(x, xh, W1, b1, W2, G1p, G2p, ei, gh);
    scan_kernel<<<NBINS, 64, 0, stream>>>(gh, gbase, tot);
    scatter_kernel<<<GCH, 256, 0, stream>>>(ei, ea, gbase, coarse);
    mid_kernel<<<NBLK_M, 256, 0, stream>>>(tot, coarse, x, xh,
                                           (const bf16x8*)G1p, (const bf16x8*)G2p,
                                           cur, seaf, slot, P2h, Q2);
    final_kernel<<<NN / 16, 256, 0, stream>>>(P2h, Q2, cur, slot, seaf, W2, b2, out);
}